// Round 1
// baseline (1014.482 us; speedup 1.0000x reference)
//
#include <hip/hip_runtime.h>

#define N_NODES  100000
#define N_EDGES  800000
#define ET       900000   // edges + self loops
#define N_GRAPHS 2000
#define IN_DIM   64
#define HID      32
#define HEADS    4
#define HF       128      // HEADS*HID
#define NEG_SLOPE 0.2f

__device__ __forceinline__ float lrelu(float x) { return x > 0.f ? x : NEG_SLOPE * x; }
__device__ __forceinline__ float elu_f(float x) { return x > 0.f ? x : expm1f(x); }

// ---------------- CSR build ----------------
__global__ void k_count(const int* __restrict__ ei, int* __restrict__ deg) {
  int e = blockIdx.x * 256 + threadIdx.x;
  if (e >= ET) return;
  int d = (e < N_EDGES) ? ei[N_EDGES + e] : (e - N_EDGES);
  atomicAdd(&deg[d], 1);
}

__global__ void k_scan1(const int* __restrict__ deg, int* __restrict__ rs, int* __restrict__ bsums) {
  __shared__ int sd[256];
  int t = threadIdx.x;
  int i = blockIdx.x * 256 + t;
  int v = (i < N_NODES) ? deg[i] : 0;
  sd[t] = v; __syncthreads();
  for (int s = 1; s < 256; s <<= 1) {
    int tmp = (t >= s) ? sd[t - s] : 0; __syncthreads();
    sd[t] += tmp; __syncthreads();
  }
  if (i < N_NODES) rs[i] = sd[t] - v;        // exclusive within block
  if (t == 255) bsums[blockIdx.x] = sd[255]; // block total
}

__global__ void k_scan2(int* __restrict__ bsums, int nb) {
  __shared__ int sd[512];
  int t = threadIdx.x;
  int v = (t < nb) ? bsums[t] : 0;
  sd[t] = v; __syncthreads();
  for (int s = 1; s < 512; s <<= 1) {
    int tmp = (t >= s) ? sd[t - s] : 0; __syncthreads();
    sd[t] += tmp; __syncthreads();
  }
  if (t < nb) bsums[t] = sd[t] - v;          // exclusive over block sums
}

__global__ void k_scan3(int* __restrict__ rs, const int* __restrict__ bsums) {
  int i = blockIdx.x * 256 + threadIdx.x;
  if (i < N_NODES) rs[i] += bsums[blockIdx.x];
  if (i == 0) rs[N_NODES] = ET;
}

__global__ void k_fill(const int* __restrict__ ei, const int* __restrict__ rs,
                       int* __restrict__ fill, int* __restrict__ csr_src) {
  int e = blockIdx.x * 256 + threadIdx.x;
  if (e >= ET) return;
  int s, d;
  if (e < N_EDGES) { s = ei[e]; d = ei[N_EDGES + e]; }
  else             { s = e - N_EDGES; d = s; }
  int pos = atomicAdd(&fill[d], 1);
  csr_src[rs[d] + pos] = s;
}

// ---------------- GEMM + attention dots ----------------
// h = X @ W  ([N,K]@[K,128]); as/ad = per-head dot of h with a_src/a_dst.
// 128 threads/block, 64 rows/block, each thread: 1 row x 64 cols (2 heads).
template<int K>
__global__ void __launch_bounds__(128) k_gemm_attn(
    const float* __restrict__ X, const float* __restrict__ W,
    const float* __restrict__ av_src, const float* __restrict__ av_dst,
    float* __restrict__ H, float* __restrict__ AS, float* __restrict__ AD) {
  constexpr int KP = K + 1;                 // padded stride: conflict-free sX reads
  __shared__ float sX[64 * KP];
  __shared__ float sW[32 * HF];             // 32 k-rows of W at a time (16 KB)
  const int t = threadIdx.x;
  const int row0 = blockIdx.x * 64;

  for (int i = t; i < 64 * K; i += 128) {
    int r = i / K, k = i % K;
    int gr = row0 + r;
    sX[r * KP + k] = (gr < N_NODES) ? X[(size_t)gr * K + k] : 0.f;
  }

  float acc[64];
#pragma unroll
  for (int j = 0; j < 64; ++j) acc[j] = 0.f;

  const int rl = t >> 1;    // local row 0..63
  const int hp = t & 1;     // head-pair: cols [hp*64, hp*64+64)

  for (int kb = 0; kb < K; kb += 32) {
    __syncthreads();
    for (int i = t; i < 32 * HF; i += 128) sW[i] = W[(size_t)kb * HF + i];
    __syncthreads();
    for (int k2 = 0; k2 < 32; ++k2) {
      float xv = sX[rl * KP + kb + k2];
      const float4* wr = (const float4*)&sW[k2 * HF + hp * 64];
#pragma unroll
      for (int j4 = 0; j4 < 16; ++j4) {
        float4 w4 = wr[j4];
        acc[4 * j4 + 0] += xv * w4.x;
        acc[4 * j4 + 1] += xv * w4.y;
        acc[4 * j4 + 2] += xv * w4.z;
        acc[4 * j4 + 3] += xv * w4.w;
      }
    }
  }

  int gr = row0 + rl;
  if (gr < N_NODES) {
    float4* hrow = (float4*)&H[(size_t)gr * HF + hp * 64];
#pragma unroll
    for (int j4 = 0; j4 < 16; ++j4)
      hrow[j4] = make_float4(acc[4 * j4], acc[4 * j4 + 1], acc[4 * j4 + 2], acc[4 * j4 + 3]);
#pragma unroll
    for (int hh = 0; hh < 2; ++hh) {
      int head = hp * 2 + hh;
      float sd = 0.f, dd = 0.f;
#pragma unroll
      for (int j = 0; j < HID; ++j) {
        float v = acc[hh * HID + j];
        sd += v * av_src[head * HID + j];
        dd += v * av_dst[head * HID + j];
      }
      AS[gr * HEADS + head] = sd;
      AD[gr * HEADS + head] = dd;
    }
  }
}

// ---------------- per-node segment softmax -> alpha per CSR slot ----------------
__global__ void k_softmax_alpha(const int* __restrict__ rs, const int* __restrict__ csr_src,
                                const float* __restrict__ AS, const float* __restrict__ AD,
                                float* __restrict__ ALPHA) {
  int n = blockIdx.x * 256 + threadIdx.x;
  if (n >= N_NODES) return;
  int b = rs[n], e = rs[n + 1];
  const float4 ad = *(const float4*)(AD + 4 * n);
  float mx = -3.4e38f, my = -3.4e38f, mz = -3.4e38f, mw = -3.4e38f;
  for (int j = b; j < e; ++j) {
    int s = csr_src[j];
    float4 as = *(const float4*)(AS + 4 * s);
    mx = fmaxf(mx, lrelu(as.x + ad.x));
    my = fmaxf(my, lrelu(as.y + ad.y));
    mz = fmaxf(mz, lrelu(as.z + ad.z));
    mw = fmaxf(mw, lrelu(as.w + ad.w));
  }
  float dx = 0.f, dy = 0.f, dz = 0.f, dw = 0.f;
  for (int j = b; j < e; ++j) {
    int s = csr_src[j];
    float4 as = *(const float4*)(AS + 4 * s);
    float4 ev;
    ev.x = expf(lrelu(as.x + ad.x) - mx);
    ev.y = expf(lrelu(as.y + ad.y) - my);
    ev.z = expf(lrelu(as.z + ad.z) - mz);
    ev.w = expf(lrelu(as.w + ad.w) - mw);
    dx += ev.x; dy += ev.y; dz += ev.z; dw += ev.w;
    *(float4*)(ALPHA + 4 * j) = ev;
  }
  float ix = 1.f / dx, iy = 1.f / dy, iz = 1.f / dz, iw = 1.f / dw;
  for (int j = b; j < e; ++j) {
    float4 a = *(const float4*)(ALPHA + 4 * j);
    a.x *= ix; a.y *= iy; a.z *= iz; a.w *= iw;
    *(float4*)(ALPHA + 4 * j) = a;
  }
}

// ---------------- weighted aggregation (+bias, +ELU; head-mean when !CONCAT) ----------------
template<bool CONCAT>
__global__ void __launch_bounds__(128) k_aggregate(
    const int* __restrict__ rs, const int* __restrict__ csr_src,
    const float* __restrict__ H, const float* __restrict__ ALPHA,
    const float* __restrict__ bias, float* __restrict__ OUT) {
  int n = blockIdx.x;
  int c = threadIdx.x;            // 0..127
  int head = c >> 5;
  int b = rs[n], e = rs[n + 1];
  float acc = 0.f;
  for (int j = b; j < e; ++j) {
    int s = csr_src[j];
    float a = ALPHA[4 * j + head];
    acc += H[(size_t)s * HF + c] * a;
  }
  if (CONCAT) {
    OUT[(size_t)n * HF + c] = elu_f(acc + bias[c]);
  } else {
    __shared__ float l[HF];
    l[c] = acc;
    __syncthreads();
    if (c < HID) {
      float v = 0.25f * (l[c] + l[c + HID] + l[c + 2 * HID] + l[c + 3 * HID]) + bias[c];
      OUT[(size_t)n * HID + c] = elu_f(v);
    }
  }
}

// ---------------- global mean pool + MLP head (one wave per graph) ----------------
__global__ void __launch_bounds__(64) k_pool_mlp(
    const int* __restrict__ batch, const float* __restrict__ H3,
    const float* __restrict__ Wm1, const float* __restrict__ bm1,
    const float* __restrict__ Wm2, const float* __restrict__ bm2,
    float* __restrict__ OUT) {
  int g = blockIdx.x;
  int t = threadIdx.x;
  __shared__ float pooled[HID];
  // lower_bound(batch, g) and lower_bound(batch, g+1) — batch is sorted.
  int lo = 0, hi = N_NODES;
  while (lo < hi) { int mid = (lo + hi) >> 1; if (batch[mid] < g) lo = mid + 1; else hi = mid; }
  int start = lo;
  hi = N_NODES;
  while (lo < hi) { int mid = (lo + hi) >> 1; if (batch[mid] < g + 1) lo = mid + 1; else hi = mid; }
  int end = lo;
  if (t < HID) {
    float s = 0.f;
    for (int n = start; n < end; ++n) s += H3[(size_t)n * HID + t];
    float cnt = (float)(end - start);
    pooled[t] = s / fmaxf(cnt, 1.f);
  }
  __syncthreads();
  float z = bm1[t];
#pragma unroll
  for (int f = 0; f < HID; ++f) z += pooled[f] * Wm1[f * 64 + t];
  z = fmaxf(z, 0.f);
  float p = z * Wm2[t];
  for (int off = 32; off > 0; off >>= 1) p += __shfl_down(p, off);
  if (t == 0) OUT[g] = p + bm2[0];
}

extern "C" void kernel_launch(void* const* d_in, const int* in_sizes, int n_in,
                              void* d_out, int out_size, void* d_ws, size_t ws_size,
                              hipStream_t stream) {
  const float* x    = (const float*)d_in[0];
  const int*   ei   = (const int*)d_in[1];
  const int*   batch= (const int*)d_in[2];
  const float* W1   = (const float*)d_in[3];
  const float* a1s  = (const float*)d_in[4];
  const float* a1d  = (const float*)d_in[5];
  const float* b1   = (const float*)d_in[6];
  const float* W2   = (const float*)d_in[7];
  const float* a2s  = (const float*)d_in[8];
  const float* a2d  = (const float*)d_in[9];
  const float* b2   = (const float*)d_in[10];
  const float* W3   = (const float*)d_in[11];
  const float* a3s  = (const float*)d_in[12];
  const float* a3d  = (const float*)d_in[13];
  const float* b3   = (const float*)d_in[14];
  const float* Wm1  = (const float*)d_in[15];
  const float* bm1  = (const float*)d_in[16];
  const float* Wm2  = (const float*)d_in[17];
  const float* bm2  = (const float*)d_in[18];
  float* out = (float*)d_out;

  char* p = (char*)d_ws;
  auto take = [&](size_t bytes) { char* r = p; p += (bytes + 255) & ~(size_t)255; return r; };
  float* bufA  = (float*)take((size_t)N_NODES * HF * 4);
  float* bufB  = (float*)take((size_t)N_NODES * HF * 4);
  float* AS    = (float*)take((size_t)N_NODES * HEADS * 4);
  float* AD    = (float*)take((size_t)N_NODES * HEADS * 4);
  float* ALPHA = (float*)take((size_t)ET * HEADS * 4);
  int*   deg   = (int*)take((size_t)N_NODES * 4);       // reused as fill counters
  int*   rs    = (int*)take((size_t)(N_NODES + 1) * 4);
  int*   csr   = (int*)take((size_t)ET * 4);
  int*   bsums = (int*)take((size_t)512 * 4);

  const int nb_scan = (N_NODES + 255) / 256;  // 391

  // CSR build (identical across layers)
  hipMemsetAsync(deg, 0, (size_t)N_NODES * 4, stream);
  k_count<<<(ET + 255) / 256, 256, 0, stream>>>(ei, deg);
  k_scan1<<<nb_scan, 256, 0, stream>>>(deg, rs, bsums);
  k_scan2<<<1, 512, 0, stream>>>(bsums, nb_scan);
  k_scan3<<<nb_scan, 256, 0, stream>>>(rs, bsums);
  hipMemsetAsync(deg, 0, (size_t)N_NODES * 4, stream);
  k_fill<<<(ET + 255) / 256, 256, 0, stream>>>(ei, rs, deg, csr);

  const int gb = (N_NODES + 63) / 64;
  const int nb = (N_NODES + 255) / 256;

  // layer 1 (K=64)
  k_gemm_attn<IN_DIM><<<gb, 128, 0, stream>>>(x, W1, a1s, a1d, bufA, AS, AD);
  k_softmax_alpha<<<nb, 256, 0, stream>>>(rs, csr, AS, AD, ALPHA);
  k_aggregate<true><<<N_NODES, 128, 0, stream>>>(rs, csr, bufA, ALPHA, b1, bufB);
  // layer 2 (K=128)
  k_gemm_attn<HF><<<gb, 128, 0, stream>>>(bufB, W2, a2s, a2d, bufA, AS, AD);
  k_softmax_alpha<<<nb, 256, 0, stream>>>(rs, csr, AS, AD, ALPHA);
  k_aggregate<true><<<N_NODES, 128, 0, stream>>>(rs, csr, bufA, ALPHA, b2, bufB);
  // layer 3 (K=128, concat=False -> head mean)
  k_gemm_attn<HF><<<gb, 128, 0, stream>>>(bufB, W3, a3s, a3d, bufA, AS, AD);
  k_softmax_alpha<<<nb, 256, 0, stream>>>(rs, csr, AS, AD, ALPHA);
  k_aggregate<false><<<N_NODES, 128, 0, stream>>>(rs, csr, bufA, ALPHA, b3, bufB);
  // pool + MLP
  k_pool_mlp<<<N_GRAPHS, 64, 0, stream>>>(batch, bufB, Wm1, bm1, Wm2, bm2, out);
}

// Round 2
// 945.000 us; speedup vs baseline: 1.0735x; 1.0735x over previous
//
#include <hip/hip_runtime.h>

#define N_NODES  100000
#define N_EDGES  800000
#define ET       900000   // edges + self loops
#define N_GRAPHS 2000
#define IN_DIM   64
#define HID      32
#define HEADS    4
#define HF       128      // HEADS*HID
#define NEG_SLOPE 0.2f

__device__ __forceinline__ float lrelu(float x) { return x > 0.f ? x : NEG_SLOPE * x; }
__device__ __forceinline__ float elu_f(float x) { return x > 0.f ? x : expm1f(x); }

// ---------------- CSR build ----------------
__global__ void k_count(const int* __restrict__ ei, int* __restrict__ deg) {
  int e = blockIdx.x * 256 + threadIdx.x;
  if (e >= ET) return;
  int d = (e < N_EDGES) ? ei[N_EDGES + e] : (e - N_EDGES);
  atomicAdd(&deg[d], 1);
}

__global__ void k_scan1(const int* __restrict__ deg, int* __restrict__ rs, int* __restrict__ bsums) {
  __shared__ int sd[256];
  int t = threadIdx.x;
  int i = blockIdx.x * 256 + t;
  int v = (i < N_NODES) ? deg[i] : 0;
  sd[t] = v; __syncthreads();
  for (int s = 1; s < 256; s <<= 1) {
    int tmp = (t >= s) ? sd[t - s] : 0; __syncthreads();
    sd[t] += tmp; __syncthreads();
  }
  if (i < N_NODES) rs[i] = sd[t] - v;
  if (t == 255) bsums[blockIdx.x] = sd[255];
}

__global__ void k_scan2(int* __restrict__ bsums, int nb) {
  __shared__ int sd[512];
  int t = threadIdx.x;
  int v = (t < nb) ? bsums[t] : 0;
  sd[t] = v; __syncthreads();
  for (int s = 1; s < 512; s <<= 1) {
    int tmp = (t >= s) ? sd[t - s] : 0; __syncthreads();
    sd[t] += tmp; __syncthreads();
  }
  if (t < nb) bsums[t] = sd[t] - v;
}

__global__ void k_scan3(int* __restrict__ rs, const int* __restrict__ bsums) {
  int i = blockIdx.x * 256 + threadIdx.x;
  if (i < N_NODES) rs[i] += bsums[blockIdx.x];
  if (i == 0) rs[N_NODES] = ET;
}

__global__ void k_fill(const int* __restrict__ ei, const int* __restrict__ rs,
                       int* __restrict__ fill, int* __restrict__ csr_src) {
  int e = blockIdx.x * 256 + threadIdx.x;
  if (e >= ET) return;
  int s, d;
  if (e < N_EDGES) { s = ei[e]; d = ei[N_EDGES + e]; }
  else             { s = e - N_EDGES; d = s; }
  int pos = atomicAdd(&fill[d], 1);
  csr_src[rs[d] + pos] = s;
}

// ---------------- GEMM + attention dots (register-blocked) ----------------
// h = X @ W ([N,K]@[K,128]) + per-head dots vs a_src/a_dst.
// Block: 256 threads, BM=256 rows x BN=128 cols. Thread tile: 8 rows x 16 cols.
// Per k: 2x ds_read_b128 (X^T) + 4x ds_read_b128 (W) feed 128 FMAs.
#define XRP 260                       // X^T row stride (pad: 2-way max conflicts)
#define WBS 516                       // W col-block stride (pad: conflict-free)
template<int K>
__global__ void __launch_bounds__(256) k_gemm_attn(
    const float* __restrict__ X, const float* __restrict__ Wg,
    const float* __restrict__ av_src, const float* __restrict__ av_dst,
    float* __restrict__ H, float* __restrict__ AS, float* __restrict__ AD) {
  __shared__ float sXT[32 * XRP];     // [k2][row] transposed chunk, 33.3 KB
  __shared__ float sW[8 * WBS];       // [c/16][k2][16] chunk, 16.5 KB
  const int t = threadIdx.x;
  const int tr = t >> 3;              // 0..31 row-group
  const int tc = t & 7;               // 0..7 col-group (16 cols)
  const int r0 = tr * 8;
  const int c0 = tc * 16;
  const int head = tc >> 1;
  const int half = tc & 1;
  const int row0 = blockIdx.x * 256;

  // attention vectors for this thread's 16 columns
  float aS[16], aD[16];
#pragma unroll
  for (int j = 0; j < 16; ++j) {
    aS[j] = av_src[head * HID + half * 16 + j];
    aD[j] = av_dst[head * HID + half * 16 + j];
  }

  float acc[8][16];
#pragma unroll
  for (int i = 0; i < 8; ++i)
#pragma unroll
    for (int j = 0; j < 16; ++j) acc[i][j] = 0.f;

  for (int kb = 0; kb < K; kb += 32) {
    __syncthreads();
    // stage X^T chunk: 256 rows x 32 k
    for (int i = t; i < 256 * 32; i += 256) {
      int kc = i & 31, r = i >> 5;
      int gr = row0 + r;
      sXT[kc * XRP + r] = (gr < N_NODES) ? X[(size_t)gr * K + kb + kc] : 0.f;
    }
    // stage W chunk: 32 k x 128 cols into [c16][k2][16]
    for (int i = t; i < 32 * 128; i += 256) {
      int k2 = i >> 7, c = i & 127;
      sW[(c >> 4) * WBS + k2 * 16 + (c & 15)] = Wg[(size_t)(kb + k2) * HF + c];
    }
    __syncthreads();
#pragma unroll 4
    for (int k2 = 0; k2 < 32; ++k2) {
      float4 x0 = *(const float4*)&sXT[k2 * XRP + r0];
      float4 x1 = *(const float4*)&sXT[k2 * XRP + r0 + 4];
      const float4* wp = (const float4*)&sW[tc * WBS + k2 * 16];
      float4 w0 = wp[0], w1 = wp[1], w2 = wp[2], w3 = wp[3];
      float xv[8] = {x0.x, x0.y, x0.z, x0.w, x1.x, x1.y, x1.z, x1.w};
      float wv[16] = {w0.x, w0.y, w0.z, w0.w, w1.x, w1.y, w1.z, w1.w,
                      w2.x, w2.y, w2.z, w2.w, w3.x, w3.y, w3.z, w3.w};
#pragma unroll
      for (int i = 0; i < 8; ++i)
#pragma unroll
        for (int j = 0; j < 16; ++j) acc[i][j] += xv[i] * wv[j];
    }
  }

  // epilogue: per-row attention dots over this thread's 16 cols, combine halves
  float pdS[8], pdD[8];
#pragma unroll
  for (int i = 0; i < 8; ++i) {
    float s = 0.f, d = 0.f;
#pragma unroll
    for (int j = 0; j < 16; ++j) { s += acc[i][j] * aS[j]; d += acc[i][j] * aD[j]; }
    pdS[i] = s; pdD[i] = d;
  }
#pragma unroll
  for (int i = 0; i < 8; ++i) {
    pdS[i] += __shfl_xor(pdS[i], 1);
    pdD[i] += __shfl_xor(pdD[i], 1);
  }

#pragma unroll
  for (int i = 0; i < 8; ++i) {
    int gr = row0 + r0 + i;
    if (gr < N_NODES) {
      float4* hrow = (float4*)&H[(size_t)gr * HF + c0];
      hrow[0] = make_float4(acc[i][0], acc[i][1], acc[i][2], acc[i][3]);
      hrow[1] = make_float4(acc[i][4], acc[i][5], acc[i][6], acc[i][7]);
      hrow[2] = make_float4(acc[i][8], acc[i][9], acc[i][10], acc[i][11]);
      hrow[3] = make_float4(acc[i][12], acc[i][13], acc[i][14], acc[i][15]);
      if (half == 0) {
        AS[gr * HEADS + head] = pdS[i];
        AD[gr * HEADS + head] = pdD[i];
      }
    }
  }
}

// ---------------- per-node segment softmax: unnormalized e + 1/denom ----------------
__global__ void k_softmax(const int* __restrict__ rs, const int* __restrict__ csr_src,
                          const float* __restrict__ AS, const float* __restrict__ AD,
                          float* __restrict__ E, float* __restrict__ INVD) {
  int n = blockIdx.x * 256 + threadIdx.x;
  if (n >= N_NODES) return;
  int b = rs[n], e = rs[n + 1];
  const float4 ad = *(const float4*)(AD + 4 * n);
  float4 m = make_float4(-3.4e38f, -3.4e38f, -3.4e38f, -3.4e38f);
  for (int j = b; j < e; ++j) {
    int s = csr_src[j];
    float4 as = *(const float4*)(AS + 4 * s);
    float4 l;
    l.x = lrelu(as.x + ad.x); l.y = lrelu(as.y + ad.y);
    l.z = lrelu(as.z + ad.z); l.w = lrelu(as.w + ad.w);
    m.x = fmaxf(m.x, l.x); m.y = fmaxf(m.y, l.y);
    m.z = fmaxf(m.z, l.z); m.w = fmaxf(m.w, l.w);
    *(float4*)(E + 4 * j) = l;        // cache logits (avoid 2nd gather of AS)
  }
  float4 d = make_float4(0.f, 0.f, 0.f, 0.f);
  for (int j = b; j < e; ++j) {
    float4 l = *(const float4*)(E + 4 * j);
    float4 ev;
    ev.x = expf(l.x - m.x); ev.y = expf(l.y - m.y);
    ev.z = expf(l.z - m.z); ev.w = expf(l.w - m.w);
    d.x += ev.x; d.y += ev.y; d.z += ev.z; d.w += ev.w;
    *(float4*)(E + 4 * j) = ev;
  }
  *(float4*)(INVD + 4 * n) = make_float4(1.f / d.x, 1.f / d.y, 1.f / d.z, 1.f / d.w);
}

// ---------------- weighted aggregation: wave per node, float2 cols ----------------
template<bool CONCAT>
__global__ void __launch_bounds__(256) k_aggregate(
    const int* __restrict__ rs, const int* __restrict__ csr_src,
    const float* __restrict__ H, const float* __restrict__ E,
    const float* __restrict__ INVD, const float* __restrict__ bias,
    float* __restrict__ OUT) {
  int n = blockIdx.x * 4 + (threadIdx.x >> 6);
  if (n >= N_NODES) return;
  int lane = threadIdx.x & 63;
  int head = lane >> 4;               // cols 2*lane, 2*lane+1 -> head = (2*lane)/32
  int b = rs[n], e = rs[n + 1];
  float a0 = 0.f, a1 = 0.f;
  for (int j = b; j < e; ++j) {
    int s = csr_src[j];
    float ev = E[4 * j + head];
    float2 h = *(const float2*)&H[(size_t)s * HF + lane * 2];
    a0 += h.x * ev; a1 += h.y * ev;
  }
  float invd = INVD[4 * n + head];
  a0 *= invd; a1 *= invd;
  if (CONCAT) {
    int c = lane * 2;
    float2 o;
    o.x = elu_f(a0 + bias[c]);
    o.y = elu_f(a1 + bias[c + 1]);
    *(float2*)&OUT[(size_t)n * HF + c] = o;
  } else {
    // mean over heads: lanes l, l^16, l^32, l^48 hold same within-head offset
    a0 += __shfl_xor(a0, 16); a0 += __shfl_xor(a0, 32);
    a1 += __shfl_xor(a1, 16); a1 += __shfl_xor(a1, 32);
    if (lane < 16) {
      int c = lane * 2;
      float2 o;
      o.x = elu_f(0.25f * a0 + bias[c]);
      o.y = elu_f(0.25f * a1 + bias[c + 1]);
      *(float2*)&OUT[(size_t)n * HID + c] = o;
    }
  }
}

// ---------------- global mean pool + MLP head (one wave per graph) ----------------
__global__ void __launch_bounds__(64) k_pool_mlp(
    const int* __restrict__ batch, const float* __restrict__ H3,
    const float* __restrict__ Wm1, const float* __restrict__ bm1,
    const float* __restrict__ Wm2, const float* __restrict__ bm2,
    float* __restrict__ OUT) {
  int g = blockIdx.x;
  int t = threadIdx.x;
  __shared__ float pooled[HID];
  int lo = 0, hi = N_NODES;
  while (lo < hi) { int mid = (lo + hi) >> 1; if (batch[mid] < g) lo = mid + 1; else hi = mid; }
  int start = lo;
  hi = N_NODES;
  while (lo < hi) { int mid = (lo + hi) >> 1; if (batch[mid] < g + 1) lo = mid + 1; else hi = mid; }
  int end = lo;
  if (t < HID) {
    float s = 0.f;
    for (int n = start; n < end; ++n) s += H3[(size_t)n * HID + t];
    float cnt = (float)(end - start);
    pooled[t] = s / fmaxf(cnt, 1.f);
  }
  __syncthreads();
  float z = bm1[t];
#pragma unroll
  for (int f = 0; f < HID; ++f) z += pooled[f] * Wm1[f * 64 + t];
  z = fmaxf(z, 0.f);
  float p = z * Wm2[t];
  for (int off = 32; off > 0; off >>= 1) p += __shfl_down(p, off);
  if (t == 0) OUT[g] = p + bm2[0];
}

extern "C" void kernel_launch(void* const* d_in, const int* in_sizes, int n_in,
                              void* d_out, int out_size, void* d_ws, size_t ws_size,
                              hipStream_t stream) {
  const float* x    = (const float*)d_in[0];
  const int*   ei   = (const int*)d_in[1];
  const int*   batch= (const int*)d_in[2];
  const float* W1   = (const float*)d_in[3];
  const float* a1s  = (const float*)d_in[4];
  const float* a1d  = (const float*)d_in[5];
  const float* b1   = (const float*)d_in[6];
  const float* W2   = (const float*)d_in[7];
  const float* a2s  = (const float*)d_in[8];
  const float* a2d  = (const float*)d_in[9];
  const float* b2   = (const float*)d_in[10];
  const float* W3   = (const float*)d_in[11];
  const float* a3s  = (const float*)d_in[12];
  const float* a3d  = (const float*)d_in[13];
  const float* b3   = (const float*)d_in[14];
  const float* Wm1  = (const float*)d_in[15];
  const float* bm1  = (const float*)d_in[16];
  const float* Wm2  = (const float*)d_in[17];
  const float* bm2  = (const float*)d_in[18];
  float* out = (float*)d_out;

  char* p = (char*)d_ws;
  auto take = [&](size_t bytes) { char* r = p; p += (bytes + 255) & ~(size_t)255; return r; };
  float* bufA  = (float*)take((size_t)N_NODES * HF * 4);
  float* bufB  = (float*)take((size_t)N_NODES * HF * 4);
  float* AS    = (float*)take((size_t)N_NODES * HEADS * 4);
  float* AD    = (float*)take((size_t)N_NODES * HEADS * 4);
  float* E     = (float*)take((size_t)ET * HEADS * 4);
  float* INVD  = (float*)take((size_t)N_NODES * HEADS * 4);
  int*   deg   = (int*)take((size_t)N_NODES * 4);       // reused as fill counters
  int*   rs    = (int*)take((size_t)(N_NODES + 1) * 4);
  int*   csr   = (int*)take((size_t)ET * 4);
  int*   bsums = (int*)take((size_t)512 * 4);

  const int nb_scan = (N_NODES + 255) / 256;  // 391

  hipMemsetAsync(deg, 0, (size_t)N_NODES * 4, stream);
  k_count<<<(ET + 255) / 256, 256, 0, stream>>>(ei, deg);
  k_scan1<<<nb_scan, 256, 0, stream>>>(deg, rs, bsums);
  k_scan2<<<1, 512, 0, stream>>>(bsums, nb_scan);
  k_scan3<<<nb_scan, 256, 0, stream>>>(rs, bsums);
  hipMemsetAsync(deg, 0, (size_t)N_NODES * 4, stream);
  k_fill<<<(ET + 255) / 256, 256, 0, stream>>>(ei, rs, deg, csr);

  const int gb = (N_NODES + 255) / 256;       // 391 blocks of 256 rows
  const int nb = (N_NODES + 255) / 256;
  const int ab = (N_NODES + 3) / 4;           // aggregate: 4 nodes/block

  // layer 1 (K=64)
  k_gemm_attn<IN_DIM><<<gb, 256, 0, stream>>>(x, W1, a1s, a1d, bufA, AS, AD);
  k_softmax<<<nb, 256, 0, stream>>>(rs, csr, AS, AD, E, INVD);
  k_aggregate<true><<<ab, 256, 0, stream>>>(rs, csr, bufA, E, INVD, b1, bufB);
  // layer 2 (K=128)
  k_gemm_attn<HF><<<gb, 256, 0, stream>>>(bufB, W2, a2s, a2d, bufA, AS, AD);
  k_softmax<<<nb, 256, 0, stream>>>(rs, csr, AS, AD, E, INVD);
  k_aggregate<true><<<ab, 256, 0, stream>>>(rs, csr, bufA, E, INVD, b2, bufB);
  // layer 3 (K=128, concat=False -> head mean)
  k_gemm_attn<HF><<<gb, 256, 0, stream>>>(bufB, W3, a3s, a3d, bufA, AS, AD);
  k_softmax<<<nb, 256, 0, stream>>>(rs, csr, AS, AD, E, INVD);
  k_aggregate<false><<<ab, 256, 0, stream>>>(rs, csr, bufA, E, INVD, b3, bufB);
  // pool + MLP
  k_pool_mlp<<<N_GRAPHS, 64, 0, stream>>>(batch, bufB, Wm1, bm1, Wm2, bm2, out);
}

// Round 3
// 737.987 us; speedup vs baseline: 1.3747x; 1.2805x over previous
//
#include <hip/hip_runtime.h>

#define N_NODES  100000
#define N_EDGES  800000
#define ET       900000   // edges + self loops
#define N_GRAPHS 2000
#define IN_DIM   64
#define HID      32
#define HEADS    4
#define HF       128      // HEADS*HID
#define NEG_SLOPE 0.2f

__device__ __forceinline__ float lrelu(float x) { return x > 0.f ? x : NEG_SLOPE * x; }
__device__ __forceinline__ float elu_f(float x) { return x > 0.f ? x : expm1f(x); }

// ---------------- CSR build ----------------
__global__ void k_count(const int* __restrict__ ei, int* __restrict__ deg) {
  int e = blockIdx.x * 256 + threadIdx.x;
  if (e >= ET) return;
  int d = (e < N_EDGES) ? ei[N_EDGES + e] : (e - N_EDGES);
  atomicAdd(&deg[d], 1);
}

__global__ void k_scan1(const int* __restrict__ deg, int* __restrict__ rs, int* __restrict__ bsums) {
  __shared__ int sd[256];
  int t = threadIdx.x;
  int i = blockIdx.x * 256 + t;
  int v = (i < N_NODES) ? deg[i] : 0;
  sd[t] = v; __syncthreads();
  for (int s = 1; s < 256; s <<= 1) {
    int tmp = (t >= s) ? sd[t - s] : 0; __syncthreads();
    sd[t] += tmp; __syncthreads();
  }
  if (i < N_NODES) rs[i] = sd[t] - v;
  if (t == 255) bsums[blockIdx.x] = sd[255];
}

__global__ void k_scan2(int* __restrict__ bsums, int nb) {
  __shared__ int sd[512];
  int t = threadIdx.x;
  int v = (t < nb) ? bsums[t] : 0;
  sd[t] = v; __syncthreads();
  for (int s = 1; s < 512; s <<= 1) {
    int tmp = (t >= s) ? sd[t - s] : 0; __syncthreads();
    sd[t] += tmp; __syncthreads();
  }
  if (t < nb) bsums[t] = sd[t] - v;
}

__global__ void k_scan3(int* __restrict__ rs, const int* __restrict__ bsums) {
  int i = blockIdx.x * 256 + threadIdx.x;
  if (i < N_NODES) rs[i] += bsums[blockIdx.x];
  if (i == 0) rs[N_NODES] = ET;
}

__global__ void k_fill(const int* __restrict__ ei, const int* __restrict__ rs,
                       int* __restrict__ fill, int* __restrict__ csr_src) {
  int e = blockIdx.x * 256 + threadIdx.x;
  if (e >= ET) return;
  int s, d;
  if (e < N_EDGES) { s = ei[e]; d = ei[N_EDGES + e]; }
  else             { s = e - N_EDGES; d = s; }
  int pos = atomicAdd(&fill[d], 1);
  csr_src[rs[d] + pos] = s;
}

// ---------------- GEMM + attention dots (occupancy-blocked) ----------------
// h = X @ W ([N,K]@[K,128]) + per-head dots vs a_src/a_dst.
// Block: 256 threads, BM=128 x BN=128. Thread tile 8x8 (64 acc VGPRs).
// Per k2: 2 ds_read_b128 (X^T, 16-lane broadcast) + 2 ds_read_b128 (W,
// swizzled 2-way) feed 64 FMAs.
#define XRS 132                        // X^T row stride (floats)
#define WRS 144                        // W k-row stride (floats)
// W swizzle: float offset within k-row = c + 4*(c>>5) -> the 16 col-group
// float4 addresses cover all 32 banks exactly 2x (2-way = free).
__device__ __forceinline__ int wofs(int c) { return c + 4 * (c >> 5); }

template<int K>
__global__ void __launch_bounds__(256) k_gemm_attn(
    const float* __restrict__ X, const float* __restrict__ Wg,
    const float* __restrict__ av_src, const float* __restrict__ av_dst,
    float* __restrict__ H, float* __restrict__ AS, float* __restrict__ AD) {
  __shared__ float sXT[32 * XRS];      // [k2][row], 16.9 KB
  __shared__ float sW[32 * WRS];       // [k2][swizzled c], 18.4 KB
  const int t = threadIdx.x;
  const int tr = t >> 4;               // 0..15
  const int tc = t & 15;               // 0..15
  const int r0 = tr * 8;
  const int c0 = tc * 8;
  const int head = tc >> 2;
  const int quar = tc & 3;
  const int row0 = blockIdx.x * 128;
  const int wbase = wofs(c0);          // swizzled W base for this thread

  float aS[8], aD[8];
#pragma unroll
  for (int j = 0; j < 8; ++j) {
    aS[j] = av_src[head * HID + quar * 8 + j];
    aD[j] = av_dst[head * HID + quar * 8 + j];
  }

  float acc[8][8];
#pragma unroll
  for (int i = 0; i < 8; ++i)
#pragma unroll
    for (int j = 0; j < 8; ++j) acc[i][j] = 0.f;

  for (int kb = 0; kb < K; kb += 32) {
    __syncthreads();
    // stage X^T chunk: 128 rows x 32 k (transpose on write)
    for (int i = t; i < 128 * 32; i += 256) {
      int kc = i & 31, r = i >> 5;
      int gr = row0 + r;
      sXT[kc * XRS + r] = (gr < N_NODES) ? X[(size_t)gr * K + kb + kc] : 0.f;
    }
    // stage W chunk: 32 k x 128 c, swizzled
    for (int i = t; i < 32 * 128; i += 256) {
      int k2 = i >> 7, c = i & 127;
      sW[k2 * WRS + wofs(c)] = Wg[(size_t)(kb + k2) * HF + c];
    }
    __syncthreads();
#pragma unroll 8
    for (int k2 = 0; k2 < 32; ++k2) {
      float4 x0 = *(const float4*)&sXT[k2 * XRS + r0];
      float4 x1 = *(const float4*)&sXT[k2 * XRS + r0 + 4];
      float4 w0 = *(const float4*)&sW[k2 * WRS + wbase];
      float4 w1 = *(const float4*)&sW[k2 * WRS + wbase + 4];
      float xv[8] = {x0.x, x0.y, x0.z, x0.w, x1.x, x1.y, x1.z, x1.w};
      float wv[8] = {w0.x, w0.y, w0.z, w0.w, w1.x, w1.y, w1.z, w1.w};
#pragma unroll
      for (int i = 0; i < 8; ++i)
#pragma unroll
        for (int j = 0; j < 8; ++j) acc[i][j] += xv[i] * wv[j];
    }
  }

  // attention dots: per-row partial over 8 cols, reduce across the 4 quarters
  float pdS[8], pdD[8];
#pragma unroll
  for (int i = 0; i < 8; ++i) {
    float s = 0.f, d = 0.f;
#pragma unroll
    for (int j = 0; j < 8; ++j) { s += acc[i][j] * aS[j]; d += acc[i][j] * aD[j]; }
    pdS[i] = s; pdD[i] = d;
  }
#pragma unroll
  for (int i = 0; i < 8; ++i) {
    pdS[i] += __shfl_xor(pdS[i], 1);  pdD[i] += __shfl_xor(pdD[i], 1);
    pdS[i] += __shfl_xor(pdS[i], 2);  pdD[i] += __shfl_xor(pdD[i], 2);
  }

#pragma unroll
  for (int i = 0; i < 8; ++i) {
    int gr = row0 + r0 + i;
    if (gr < N_NODES) {
      float4* hrow = (float4*)&H[(size_t)gr * HF + c0];
      hrow[0] = make_float4(acc[i][0], acc[i][1], acc[i][2], acc[i][3]);
      hrow[1] = make_float4(acc[i][4], acc[i][5], acc[i][6], acc[i][7]);
      if (quar == 0) {
        AS[gr * HEADS + head] = pdS[i];
        AD[gr * HEADS + head] = pdD[i];
      }
    }
  }
}

// ---------------- per-node segment softmax: unnormalized e + 1/denom ----------------
__global__ void k_softmax(const int* __restrict__ rs, const int* __restrict__ csr_src,
                          const float* __restrict__ AS, const float* __restrict__ AD,
                          float* __restrict__ E, float* __restrict__ INVD) {
  int n = blockIdx.x * 256 + threadIdx.x;
  if (n >= N_NODES) return;
  int b = rs[n], e = rs[n + 1];
  const float4 ad = *(const float4*)(AD + 4 * n);
  float4 m = make_float4(-3.4e38f, -3.4e38f, -3.4e38f, -3.4e38f);
  for (int j = b; j < e; ++j) {
    int s = csr_src[j];
    float4 as = *(const float4*)(AS + 4 * s);
    float4 l;
    l.x = lrelu(as.x + ad.x); l.y = lrelu(as.y + ad.y);
    l.z = lrelu(as.z + ad.z); l.w = lrelu(as.w + ad.w);
    m.x = fmaxf(m.x, l.x); m.y = fmaxf(m.y, l.y);
    m.z = fmaxf(m.z, l.z); m.w = fmaxf(m.w, l.w);
    *(float4*)(E + 4 * j) = l;        // cache logits (avoid 2nd gather of AS)
  }
  float4 d = make_float4(0.f, 0.f, 0.f, 0.f);
  for (int j = b; j < e; ++j) {
    float4 l = *(const float4*)(E + 4 * j);
    float4 ev;
    ev.x = expf(l.x - m.x); ev.y = expf(l.y - m.y);
    ev.z = expf(l.z - m.z); ev.w = expf(l.w - m.w);
    d.x += ev.x; d.y += ev.y; d.z += ev.z; d.w += ev.w;
    *(float4*)(E + 4 * j) = ev;
  }
  *(float4*)(INVD + 4 * n) = make_float4(1.f / d.x, 1.f / d.y, 1.f / d.z, 1.f / d.w);
}

// ---------------- weighted aggregation: wave per node, float2 cols ----------------
template<bool CONCAT>
__global__ void __launch_bounds__(256) k_aggregate(
    const int* __restrict__ rs, const int* __restrict__ csr_src,
    const float* __restrict__ H, const float* __restrict__ E,
    const float* __restrict__ INVD, const float* __restrict__ bias,
    float* __restrict__ OUT) {
  int n = blockIdx.x * 4 + (threadIdx.x >> 6);
  if (n >= N_NODES) return;
  int lane = threadIdx.x & 63;
  int head = lane >> 4;
  int b = rs[n], e = rs[n + 1];
  float a0 = 0.f, a1 = 0.f;
  for (int j = b; j < e; ++j) {
    int s = csr_src[j];
    float ev = E[4 * j + head];
    float2 h = *(const float2*)&H[(size_t)s * HF + lane * 2];
    a0 += h.x * ev; a1 += h.y * ev;
  }
  float invd = INVD[4 * n + head];
  a0 *= invd; a1 *= invd;
  if (CONCAT) {
    int c = lane * 2;
    float2 o;
    o.x = elu_f(a0 + bias[c]);
    o.y = elu_f(a1 + bias[c + 1]);
    *(float2*)&OUT[(size_t)n * HF + c] = o;
  } else {
    a0 += __shfl_xor(a0, 16); a0 += __shfl_xor(a0, 32);
    a1 += __shfl_xor(a1, 16); a1 += __shfl_xor(a1, 32);
    if (lane < 16) {
      int c = lane * 2;
      float2 o;
      o.x = elu_f(0.25f * a0 + bias[c]);
      o.y = elu_f(0.25f * a1 + bias[c + 1]);
      *(float2*)&OUT[(size_t)n * HID + c] = o;
    }
  }
}

// ---------------- global mean pool + MLP head (one wave per graph) ----------------
__global__ void __launch_bounds__(64) k_pool_mlp(
    const int* __restrict__ batch, const float* __restrict__ H3,
    const float* __restrict__ Wm1, const float* __restrict__ bm1,
    const float* __restrict__ Wm2, const float* __restrict__ bm2,
    float* __restrict__ OUT) {
  int g = blockIdx.x;
  int t = threadIdx.x;
  __shared__ float pooled[HID];
  int lo = 0, hi = N_NODES;
  while (lo < hi) { int mid = (lo + hi) >> 1; if (batch[mid] < g) lo = mid + 1; else hi = mid; }
  int start = lo;
  hi = N_NODES;
  while (lo < hi) { int mid = (lo + hi) >> 1; if (batch[mid] < g + 1) lo = mid + 1; else hi = mid; }
  int end = lo;
  if (t < HID) {
    float s = 0.f;
    for (int n = start; n < end; ++n) s += H3[(size_t)n * HID + t];
    float cnt = (float)(end - start);
    pooled[t] = s / fmaxf(cnt, 1.f);
  }
  __syncthreads();
  float z = bm1[t];
#pragma unroll
  for (int f = 0; f < HID; ++f) z += pooled[f] * Wm1[f * 64 + t];
  z = fmaxf(z, 0.f);
  float p = z * Wm2[t];
  for (int off = 32; off > 0; off >>= 1) p += __shfl_down(p, off);
  if (t == 0) OUT[g] = p + bm2[0];
}

extern "C" void kernel_launch(void* const* d_in, const int* in_sizes, int n_in,
                              void* d_out, int out_size, void* d_ws, size_t ws_size,
                              hipStream_t stream) {
  const float* x    = (const float*)d_in[0];
  const int*   ei   = (const int*)d_in[1];
  const int*   batch= (const int*)d_in[2];
  const float* W1   = (const float*)d_in[3];
  const float* a1s  = (const float*)d_in[4];
  const float* a1d  = (const float*)d_in[5];
  const float* b1   = (const float*)d_in[6];
  const float* W2   = (const float*)d_in[7];
  const float* a2s  = (const float*)d_in[8];
  const float* a2d  = (const float*)d_in[9];
  const float* b2   = (const float*)d_in[10];
  const float* W3   = (const float*)d_in[11];
  const float* a3s  = (const float*)d_in[12];
  const float* a3d  = (const float*)d_in[13];
  const float* b3   = (const float*)d_in[14];
  const float* Wm1  = (const float*)d_in[15];
  const float* bm1  = (const float*)d_in[16];
  const float* Wm2  = (const float*)d_in[17];
  const float* bm2  = (const float*)d_in[18];
  float* out = (float*)d_out;

  char* p = (char*)d_ws;
  auto take = [&](size_t bytes) { char* r = p; p += (bytes + 255) & ~(size_t)255; return r; };
  float* bufA  = (float*)take((size_t)N_NODES * HF * 4);
  float* bufB  = (float*)take((size_t)N_NODES * HF * 4);
  float* AS    = (float*)take((size_t)N_NODES * HEADS * 4);
  float* AD    = (float*)take((size_t)N_NODES * HEADS * 4);
  float* E     = (float*)take((size_t)ET * HEADS * 4);
  float* INVD  = (float*)take((size_t)N_NODES * HEADS * 4);
  int*   deg   = (int*)take((size_t)N_NODES * 4);       // reused as fill counters
  int*   rs    = (int*)take((size_t)(N_NODES + 1) * 4);
  int*   csr   = (int*)take((size_t)ET * 4);
  int*   bsums = (int*)take((size_t)512 * 4);

  const int nb_scan = (N_NODES + 255) / 256;  // 391

  hipMemsetAsync(deg, 0, (size_t)N_NODES * 4, stream);
  k_count<<<(ET + 255) / 256, 256, 0, stream>>>(ei, deg);
  k_scan1<<<nb_scan, 256, 0, stream>>>(deg, rs, bsums);
  k_scan2<<<1, 512, 0, stream>>>(bsums, nb_scan);
  k_scan3<<<nb_scan, 256, 0, stream>>>(rs, bsums);
  hipMemsetAsync(deg, 0, (size_t)N_NODES * 4, stream);
  k_fill<<<(ET + 255) / 256, 256, 0, stream>>>(ei, rs, deg, csr);

  const int gb = (N_NODES + 127) / 128;       // 782 blocks of 128 rows
  const int nb = (N_NODES + 255) / 256;
  const int ab = (N_NODES + 3) / 4;           // aggregate: 4 nodes/block

  // layer 1 (K=64)
  k_gemm_attn<IN_DIM><<<gb, 256, 0, stream>>>(x, W1, a1s, a1d, bufA, AS, AD);
  k_softmax<<<nb, 256, 0, stream>>>(rs, csr, AS, AD, E, INVD);
  k_aggregate<true><<<ab, 256, 0, stream>>>(rs, csr, bufA, E, INVD, b1, bufB);
  // layer 2 (K=128)
  k_gemm_attn<HF><<<gb, 256, 0, stream>>>(bufB, W2, a2s, a2d, bufA, AS, AD);
  k_softmax<<<nb, 256, 0, stream>>>(rs, csr, AS, AD, E, INVD);
  k_aggregate<true><<<ab, 256, 0, stream>>>(rs, csr, bufA, E, INVD, b2, bufB);
  // layer 3 (K=128, concat=False -> head mean)
  k_gemm_attn<HF><<<gb, 256, 0, stream>>>(bufB, W3, a3s, a3d, bufA, AS, AD);
  k_softmax<<<nb, 256, 0, stream>>>(rs, csr, AS, AD, E, INVD);
  k_aggregate<false><<<ab, 256, 0, stream>>>(rs, csr, bufA, E, INVD, b3, bufB);
  // pool + MLP
  k_pool_mlp<<<N_GRAPHS, 64, 0, stream>>>(batch, bufB, Wm1, bm1, Wm2, bm2, out);
}

// Round 4
// 645.015 us; speedup vs baseline: 1.5728x; 1.1441x over previous
//
#include <hip/hip_runtime.h>

#define N_NODES  100000
#define N_EDGES  800000
#define ET       900000   // edges + self loops
#define N_GRAPHS 2000
#define IN_DIM   64
#define HID      32
#define HEADS    4
#define HF       128      // HEADS*HID
#define NEG_SLOPE 0.2f

__device__ __forceinline__ float lrelu(float x) { return x > 0.f ? x : NEG_SLOPE * x; }
__device__ __forceinline__ float elu_f(float x) { return x > 0.f ? x : expm1f(x); }

// ---------------- CSR build ----------------
__global__ void k_count(const int* __restrict__ ei, int* __restrict__ deg) {
  int e = blockIdx.x * 256 + threadIdx.x;
  if (e >= ET) return;
  int d = (e < N_EDGES) ? ei[N_EDGES + e] : (e - N_EDGES);
  atomicAdd(&deg[d], 1);
}

__global__ void k_scan1(const int* __restrict__ deg, int* __restrict__ rs, int* __restrict__ bsums) {
  __shared__ int sd[256];
  int t = threadIdx.x;
  int i = blockIdx.x * 256 + t;
  int v = (i < N_NODES) ? deg[i] : 0;
  sd[t] = v; __syncthreads();
  for (int s = 1; s < 256; s <<= 1) {
    int tmp = (t >= s) ? sd[t - s] : 0; __syncthreads();
    sd[t] += tmp; __syncthreads();
  }
  if (i < N_NODES) rs[i] = sd[t] - v;
  if (t == 255) bsums[blockIdx.x] = sd[255];
}

__global__ void k_scan2(int* __restrict__ bsums, int nb) {
  __shared__ int sd[512];
  int t = threadIdx.x;
  int v = (t < nb) ? bsums[t] : 0;
  sd[t] = v; __syncthreads();
  for (int s = 1; s < 512; s <<= 1) {
    int tmp = (t >= s) ? sd[t - s] : 0; __syncthreads();
    sd[t] += tmp; __syncthreads();
  }
  if (t < nb) bsums[t] = sd[t] - v;
}

__global__ void k_scan3(int* __restrict__ rs, const int* __restrict__ bsums) {
  int i = blockIdx.x * 256 + threadIdx.x;
  if (i < N_NODES) rs[i] += bsums[blockIdx.x];
  if (i == 0) rs[N_NODES] = ET;
}

__global__ void k_fill(const int* __restrict__ ei, const int* __restrict__ rs,
                       int* __restrict__ fill, int* __restrict__ csr_src) {
  int e = blockIdx.x * 256 + threadIdx.x;
  if (e >= ET) return;
  int s, d;
  if (e < N_EDGES) { s = ei[e]; d = ei[N_EDGES + e]; }
  else             { s = e - N_EDGES; d = s; }
  int pos = atomicAdd(&fill[d], 1);
  csr_src[rs[d] + pos] = s;
}

// ---------------- GEMM + attention dots (occupancy-blocked) ----------------
#define XRS 132                        // X^T row stride (floats)
#define WRS 144                        // W k-row stride (floats)
__device__ __forceinline__ int wofs(int c) { return c + 4 * (c >> 5); }

template<int K>
__global__ void __launch_bounds__(256) k_gemm_attn(
    const float* __restrict__ X, const float* __restrict__ Wg,
    const float* __restrict__ av_src, const float* __restrict__ av_dst,
    float* __restrict__ H, float* __restrict__ AS, float* __restrict__ AD) {
  __shared__ float sXT[32 * XRS];      // [k2][row], 16.9 KB
  __shared__ float sW[32 * WRS];       // [k2][swizzled c], 18.4 KB
  const int t = threadIdx.x;
  const int tr = t >> 4;               // 0..15
  const int tc = t & 15;               // 0..15
  const int r0 = tr * 8;
  const int c0 = tc * 8;
  const int head = tc >> 2;
  const int quar = tc & 3;
  const int row0 = blockIdx.x * 128;
  const int wbase = wofs(c0);

  float aS[8], aD[8];
#pragma unroll
  for (int j = 0; j < 8; ++j) {
    aS[j] = av_src[head * HID + quar * 8 + j];
    aD[j] = av_dst[head * HID + quar * 8 + j];
  }

  float acc[8][8];
#pragma unroll
  for (int i = 0; i < 8; ++i)
#pragma unroll
    for (int j = 0; j < 8; ++j) acc[i][j] = 0.f;

  for (int kb = 0; kb < K; kb += 32) {
    __syncthreads();
    for (int i = t; i < 128 * 32; i += 256) {
      int kc = i & 31, r = i >> 5;
      int gr = row0 + r;
      sXT[kc * XRS + r] = (gr < N_NODES) ? X[(size_t)gr * K + kb + kc] : 0.f;
    }
    for (int i = t; i < 32 * 128; i += 256) {
      int k2 = i >> 7, c = i & 127;
      sW[k2 * WRS + wofs(c)] = Wg[(size_t)(kb + k2) * HF + c];
    }
    __syncthreads();
#pragma unroll 8
    for (int k2 = 0; k2 < 32; ++k2) {
      float4 x0 = *(const float4*)&sXT[k2 * XRS + r0];
      float4 x1 = *(const float4*)&sXT[k2 * XRS + r0 + 4];
      float4 w0 = *(const float4*)&sW[k2 * WRS + wbase];
      float4 w1 = *(const float4*)&sW[k2 * WRS + wbase + 4];
      float xv[8] = {x0.x, x0.y, x0.z, x0.w, x1.x, x1.y, x1.z, x1.w};
      float wv[8] = {w0.x, w0.y, w0.z, w0.w, w1.x, w1.y, w1.z, w1.w};
#pragma unroll
      for (int i = 0; i < 8; ++i)
#pragma unroll
        for (int j = 0; j < 8; ++j) acc[i][j] += xv[i] * wv[j];
    }
  }

  float pdS[8], pdD[8];
#pragma unroll
  for (int i = 0; i < 8; ++i) {
    float s = 0.f, d = 0.f;
#pragma unroll
    for (int j = 0; j < 8; ++j) { s += acc[i][j] * aS[j]; d += acc[i][j] * aD[j]; }
    pdS[i] = s; pdD[i] = d;
  }
#pragma unroll
  for (int i = 0; i < 8; ++i) {
    pdS[i] += __shfl_xor(pdS[i], 1);  pdD[i] += __shfl_xor(pdD[i], 1);
    pdS[i] += __shfl_xor(pdS[i], 2);  pdD[i] += __shfl_xor(pdD[i], 2);
  }

#pragma unroll
  for (int i = 0; i < 8; ++i) {
    int gr = row0 + r0 + i;
    if (gr < N_NODES) {
      float4* hrow = (float4*)&H[(size_t)gr * HF + c0];
      hrow[0] = make_float4(acc[i][0], acc[i][1], acc[i][2], acc[i][3]);
      hrow[1] = make_float4(acc[i][4], acc[i][5], acc[i][6], acc[i][7]);
      if (quar == 0) {
        AS[gr * HEADS + head] = pdS[i];
        AD[gr * HEADS + head] = pdD[i];
      }
    }
  }
}

// ---------------- per-node segment softmax: unnormalized e + 1/denom ----------------
__global__ void k_softmax(const int* __restrict__ rs, const int* __restrict__ csr_src,
                          const float* __restrict__ AS, const float* __restrict__ AD,
                          float* __restrict__ E, float* __restrict__ INVD) {
  int n = blockIdx.x * 256 + threadIdx.x;
  if (n >= N_NODES) return;
  int b = rs[n], e = rs[n + 1];
  const float4 ad = *(const float4*)(AD + 4 * n);
  float4 m = make_float4(-3.4e38f, -3.4e38f, -3.4e38f, -3.4e38f);
  for (int j = b; j < e; ++j) {
    int s = csr_src[j];
    float4 as = *(const float4*)(AS + 4 * s);
    float4 l;
    l.x = lrelu(as.x + ad.x); l.y = lrelu(as.y + ad.y);
    l.z = lrelu(as.z + ad.z); l.w = lrelu(as.w + ad.w);
    m.x = fmaxf(m.x, l.x); m.y = fmaxf(m.y, l.y);
    m.z = fmaxf(m.z, l.z); m.w = fmaxf(m.w, l.w);
    *(float4*)(E + 4 * j) = l;
  }
  float4 d = make_float4(0.f, 0.f, 0.f, 0.f);
  for (int j = b; j < e; ++j) {
    float4 l = *(const float4*)(E + 4 * j);
    float4 ev;
    ev.x = expf(l.x - m.x); ev.y = expf(l.y - m.y);
    ev.z = expf(l.z - m.z); ev.w = expf(l.w - m.w);
    d.x += ev.x; d.y += ev.y; d.z += ev.z; d.w += ev.w;
    *(float4*)(E + 4 * j) = ev;
  }
  *(float4*)(INVD + 4 * n) = make_float4(1.f / d.x, 1.f / d.y, 1.f / d.z, 1.f / d.w);
}

// ---------------- weighted aggregation: wave/node, half-wave/edge, float4 ----
// Lanes 0-31 take even CSR slots, 32-63 odd slots; each lane loads float4 of
// the 512B H row. 2x manual unroll -> 4 gather chains in flight per wave.
template<bool CONCAT>
__global__ void __launch_bounds__(256) k_aggregate(
    const int* __restrict__ rs, const int* __restrict__ csr_src,
    const float* __restrict__ H, const float* __restrict__ E,
    const float* __restrict__ INVD, const float* __restrict__ bias,
    float* __restrict__ OUT) {
  int n = blockIdx.x * 4 + (threadIdx.x >> 6);
  if (n >= N_NODES) return;
  int lane = threadIdx.x & 63;
  int half = lane >> 5;               // edge-slot parity
  int l = lane & 31;
  int c = l * 4;                      // this lane's 4 columns
  int head = l >> 3;
  int b = rs[n], e = rs[n + 1];

  float ax = 0.f, ay = 0.f, az = 0.f, aw = 0.f;
  int jj = b + half;
  for (; jj + 2 < e; jj += 4) {       // two edges per step for this half
    int s0 = csr_src[jj];
    int s1 = csr_src[jj + 2];
    float e0 = E[4 * jj + head];
    float e1 = E[4 * (jj + 2) + head];
    float4 h0 = *(const float4*)&H[(size_t)s0 * HF + c];
    float4 h1 = *(const float4*)&H[(size_t)s1 * HF + c];
    ax += h0.x * e0 + h1.x * e1;
    ay += h0.y * e0 + h1.y * e1;
    az += h0.z * e0 + h1.z * e1;
    aw += h0.w * e0 + h1.w * e1;
  }
  if (jj < e) {
    int s0 = csr_src[jj];
    float e0 = E[4 * jj + head];
    float4 h0 = *(const float4*)&H[(size_t)s0 * HF + c];
    ax += h0.x * e0; ay += h0.y * e0; az += h0.z * e0; aw += h0.w * e0;
  }
  // combine the two halves
  ax += __shfl_xor(ax, 32); ay += __shfl_xor(ay, 32);
  az += __shfl_xor(az, 32); aw += __shfl_xor(aw, 32);

  float invd = INVD[4 * n + head];
  if (CONCAT) {
    if (half == 0) {
      float4 o;
      o.x = elu_f(ax * invd + bias[c]);
      o.y = elu_f(ay * invd + bias[c + 1]);
      o.z = elu_f(az * invd + bias[c + 2]);
      o.w = elu_f(aw * invd + bias[c + 3]);
      *(float4*)&OUT[(size_t)n * HF + c] = o;
    }
  } else {
    // scale per-head first, then mean over heads (lanes differing in bits 3,4 of l)
    ax *= invd; ay *= invd; az *= invd; aw *= invd;
    ax += __shfl_xor(ax, 8);  ay += __shfl_xor(ay, 8);
    az += __shfl_xor(az, 8);  aw += __shfl_xor(aw, 8);
    ax += __shfl_xor(ax, 16); ay += __shfl_xor(ay, 16);
    az += __shfl_xor(az, 16); aw += __shfl_xor(aw, 16);
    if (lane < 8) {
      int cc = l * 4;                 // 0..28
      float4 o;
      o.x = elu_f(0.25f * ax + bias[cc]);
      o.y = elu_f(0.25f * ay + bias[cc + 1]);
      o.z = elu_f(0.25f * az + bias[cc + 2]);
      o.w = elu_f(0.25f * aw + bias[cc + 3]);
      *(float4*)&OUT[(size_t)n * HID + cc] = o;
    }
  }
}

// ---------------- global mean pool + MLP head (one wave per graph) ----------------
__global__ void __launch_bounds__(64) k_pool_mlp(
    const int* __restrict__ batch, const float* __restrict__ H3,
    const float* __restrict__ Wm1, const float* __restrict__ bm1,
    const float* __restrict__ Wm2, const float* __restrict__ bm2,
    float* __restrict__ OUT) {
  int g = blockIdx.x;
  int t = threadIdx.x;
  __shared__ float pooled[HID];
  int lo = 0, hi = N_NODES;
  while (lo < hi) { int mid = (lo + hi) >> 1; if (batch[mid] < g) lo = mid + 1; else hi = mid; }
  int start = lo;
  hi = N_NODES;
  while (lo < hi) { int mid = (lo + hi) >> 1; if (batch[mid] < g + 1) lo = mid + 1; else hi = mid; }
  int end = lo;
  if (t < HID) {
    float s = 0.f;
    for (int n = start; n < end; ++n) s += H3[(size_t)n * HID + t];
    float cnt = (float)(end - start);
    pooled[t] = s / fmaxf(cnt, 1.f);
  }
  __syncthreads();
  float z = bm1[t];
#pragma unroll
  for (int f = 0; f < HID; ++f) z += pooled[f] * Wm1[f * 64 + t];
  z = fmaxf(z, 0.f);
  float p = z * Wm2[t];
  for (int off = 32; off > 0; off >>= 1) p += __shfl_down(p, off);
  if (t == 0) OUT[g] = p + bm2[0];
}

extern "C" void kernel_launch(void* const* d_in, const int* in_sizes, int n_in,
                              void* d_out, int out_size, void* d_ws, size_t ws_size,
                              hipStream_t stream) {
  const float* x    = (const float*)d_in[0];
  const int*   ei   = (const int*)d_in[1];
  const int*   batch= (const int*)d_in[2];
  const float* W1   = (const float*)d_in[3];
  const float* a1s  = (const float*)d_in[4];
  const float* a1d  = (const float*)d_in[5];
  const float* b1   = (const float*)d_in[6];
  const float* W2   = (const float*)d_in[7];
  const float* a2s  = (const float*)d_in[8];
  const float* a2d  = (const float*)d_in[9];
  const float* b2   = (const float*)d_in[10];
  const float* W3   = (const float*)d_in[11];
  const float* a3s  = (const float*)d_in[12];
  const float* a3d  = (const float*)d_in[13];
  const float* b3   = (const float*)d_in[14];
  const float* Wm1  = (const float*)d_in[15];
  const float* bm1  = (const float*)d_in[16];
  const float* Wm2  = (const float*)d_in[17];
  const float* bm2  = (const float*)d_in[18];
  float* out = (float*)d_out;

  char* p = (char*)d_ws;
  auto take = [&](size_t bytes) { char* r = p; p += (bytes + 255) & ~(size_t)255; return r; };
  float* bufA  = (float*)take((size_t)N_NODES * HF * 4);
  float* bufB  = (float*)take((size_t)N_NODES * HF * 4);
  float* AS    = (float*)take((size_t)N_NODES * HEADS * 4);
  float* AD    = (float*)take((size_t)N_NODES * HEADS * 4);
  float* E     = (float*)take((size_t)ET * HEADS * 4);
  float* INVD  = (float*)take((size_t)N_NODES * HEADS * 4);
  int*   deg   = (int*)take((size_t)N_NODES * 4);       // reused as fill counters
  int*   rs    = (int*)take((size_t)(N_NODES + 1) * 4);
  int*   csr   = (int*)take((size_t)ET * 4);
  int*   bsums = (int*)take((size_t)512 * 4);

  const int nb_scan = (N_NODES + 255) / 256;  // 391

  hipMemsetAsync(deg, 0, (size_t)N_NODES * 4, stream);
  k_count<<<(ET + 255) / 256, 256, 0, stream>>>(ei, deg);
  k_scan1<<<nb_scan, 256, 0, stream>>>(deg, rs, bsums);
  k_scan2<<<1, 512, 0, stream>>>(bsums, nb_scan);
  k_scan3<<<nb_scan, 256, 0, stream>>>(rs, bsums);
  hipMemsetAsync(deg, 0, (size_t)N_NODES * 4, stream);
  k_fill<<<(ET + 255) / 256, 256, 0, stream>>>(ei, rs, deg, csr);

  const int gb = (N_NODES + 127) / 128;       // 782 blocks of 128 rows
  const int nb = (N_NODES + 255) / 256;
  const int ab = (N_NODES + 3) / 4;           // aggregate: 4 nodes/block

  // layer 1 (K=64)
  k_gemm_attn<IN_DIM><<<gb, 256, 0, stream>>>(x, W1, a1s, a1d, bufA, AS, AD);
  k_softmax<<<nb, 256, 0, stream>>>(rs, csr, AS, AD, E, INVD);
  k_aggregate<true><<<ab, 256, 0, stream>>>(rs, csr, bufA, E, INVD, b1, bufB);
  // layer 2 (K=128)
  k_gemm_attn<HF><<<gb, 256, 0, stream>>>(bufB, W2, a2s, a2d, bufA, AS, AD);
  k_softmax<<<nb, 256, 0, stream>>>(rs, csr, AS, AD, E, INVD);
  k_aggregate<true><<<ab, 256, 0, stream>>>(rs, csr, bufA, E, INVD, b2, bufB);
  // layer 3 (K=128, concat=False -> head mean)
  k_gemm_attn<HF><<<gb, 256, 0, stream>>>(bufB, W3, a3s, a3d, bufA, AS, AD);
  k_softmax<<<nb, 256, 0, stream>>>(rs, csr, AS, AD, E, INVD);
  k_aggregate<false><<<ab, 256, 0, stream>>>(rs, csr, bufA, E, INVD, b3, bufB);
  // pool + MLP
  k_pool_mlp<<<N_GRAPHS, 64, 0, stream>>>(batch, bufB, Wm1, bm1, Wm2, bm2, out);
}

// Round 5
// 584.065 us; speedup vs baseline: 1.7369x; 1.1044x over previous
//
#include <hip/hip_runtime.h>

#define N_NODES  100000
#define N_EDGES  800000
#define ET       900000   // edges + self loops
#define N_GRAPHS 2000
#define IN_DIM   64
#define HID      32
#define HEADS    4
#define HF       128      // HEADS*HID
#define NEG_SLOPE 0.2f

__device__ __forceinline__ float lrelu(float x) { return x > 0.f ? x : NEG_SLOPE * x; }
__device__ __forceinline__ float elu_f(float x) { return x > 0.f ? x : expm1f(x); }
// order-preserving float<->uint encode for atomicMax over signed floats
__device__ __forceinline__ unsigned fenc(float f) {
  unsigned u = __float_as_uint(f);
  return (u & 0x80000000u) ? ~u : (u | 0x80000000u);
}
__device__ __forceinline__ float fdec(unsigned e) {
  return __uint_as_float((e & 0x80000000u) ? (e ^ 0x80000000u) : ~e);
}

// ---------------- CSR build ----------------
__global__ void k_count(const int* __restrict__ ei, int* __restrict__ deg) {
  int e = blockIdx.x * 256 + threadIdx.x;
  if (e >= ET) return;
  int d = (e < N_EDGES) ? ei[N_EDGES + e] : (e - N_EDGES);
  atomicAdd(&deg[d], 1);
}

__global__ void k_scan1(const int* __restrict__ deg, int* __restrict__ rs, int* __restrict__ bsums) {
  __shared__ int sd[256];
  int t = threadIdx.x;
  int i = blockIdx.x * 256 + t;
  int v = (i < N_NODES) ? deg[i] : 0;
  sd[t] = v; __syncthreads();
  for (int s = 1; s < 256; s <<= 1) {
    int tmp = (t >= s) ? sd[t - s] : 0; __syncthreads();
    sd[t] += tmp; __syncthreads();
  }
  if (i < N_NODES) rs[i] = sd[t] - v;
  if (t == 255) bsums[blockIdx.x] = sd[255];
}

__global__ void k_scan2(int* __restrict__ bsums, int nb) {
  __shared__ int sd[512];
  int t = threadIdx.x;
  int v = (t < nb) ? bsums[t] : 0;
  sd[t] = v; __syncthreads();
  for (int s = 1; s < 512; s <<= 1) {
    int tmp = (t >= s) ? sd[t - s] : 0; __syncthreads();
    sd[t] += tmp; __syncthreads();
  }
  if (t < nb) bsums[t] = sd[t] - v;
}

__global__ void k_scan3(int* __restrict__ rs, const int* __restrict__ bsums) {
  int i = blockIdx.x * 256 + threadIdx.x;
  if (i < N_NODES) rs[i] += bsums[blockIdx.x];
  if (i == 0) rs[N_NODES] = ET;
}

__global__ void k_fill(const int* __restrict__ ei, const int* __restrict__ rs,
                       int* __restrict__ fill, int* __restrict__ csr_src) {
  int e = blockIdx.x * 256 + threadIdx.x;
  if (e >= ET) return;
  int s, d;
  if (e < N_EDGES) { s = ei[e]; d = ei[N_EDGES + e]; }
  else             { s = e - N_EDGES; d = s; }
  int pos = atomicAdd(&fill[d], 1);
  csr_src[rs[d] + pos] = s;
}

// ---------------- GEMM + attention dots ----------------
// __launch_bounds__(256,4): 128 VGPRs so the 8x8 fp32 accumulator lives in
// arch VGPRs (no accvgpr shuffling); grid is ~3 blocks/CU so 4 blocks/CU cap
// costs nothing.
#define XRS 132                        // X^T row stride (floats)
#define WRS 144                        // W k-row stride (floats)
__device__ __forceinline__ int wofs(int c) { return c + 4 * (c >> 5); }

template<int K>
__global__ void __launch_bounds__(256, 4) k_gemm_attn(
    const float* __restrict__ X, const float* __restrict__ Wg,
    const float* __restrict__ av_src, const float* __restrict__ av_dst,
    float* __restrict__ H, float* __restrict__ AS, float* __restrict__ AD) {
  __shared__ float sXT[32 * XRS];      // [k2][row], 16.9 KB
  __shared__ float sW[32 * WRS];       // [k2][swizzled c], 18.4 KB
  const int t = threadIdx.x;
  const int tr = t >> 4;               // 0..15
  const int tc = t & 15;               // 0..15
  const int r0 = tr * 8;
  const int c0 = tc * 8;
  const int head = tc >> 2;
  const int quar = tc & 3;
  const int row0 = blockIdx.x * 128;
  const int wbase = wofs(c0);

  float acc[8][8];
#pragma unroll
  for (int i = 0; i < 8; ++i)
#pragma unroll
    for (int j = 0; j < 8; ++j) acc[i][j] = 0.f;

  for (int kb = 0; kb < K; kb += 32) {
    __syncthreads();
    for (int i = t; i < 128 * 32; i += 256) {
      int kc = i & 31, r = i >> 5;
      int gr = row0 + r;
      sXT[kc * XRS + r] = (gr < N_NODES) ? X[(size_t)gr * K + kb + kc] : 0.f;
    }
    for (int i = t; i < 32 * 128; i += 256) {
      int k2 = i >> 7, c = i & 127;
      sW[k2 * WRS + wofs(c)] = Wg[(size_t)(kb + k2) * HF + c];
    }
    __syncthreads();
#pragma unroll 8
    for (int k2 = 0; k2 < 32; ++k2) {
      float4 x0 = *(const float4*)&sXT[k2 * XRS + r0];
      float4 x1 = *(const float4*)&sXT[k2 * XRS + r0 + 4];
      float4 w0 = *(const float4*)&sW[k2 * WRS + wbase];
      float4 w1 = *(const float4*)&sW[k2 * WRS + wbase + 4];
      float xv[8] = {x0.x, x0.y, x0.z, x0.w, x1.x, x1.y, x1.z, x1.w};
      float wv[8] = {w0.x, w0.y, w0.z, w0.w, w1.x, w1.y, w1.z, w1.w};
#pragma unroll
      for (int i = 0; i < 8; ++i)
#pragma unroll
        for (int j = 0; j < 8; ++j) acc[i][j] += xv[i] * wv[j];
    }
  }

  // epilogue: load attention vectors only now (short live range)
  float aS[8], aD[8];
#pragma unroll
  for (int j = 0; j < 8; ++j) {
    aS[j] = av_src[head * HID + quar * 8 + j];
    aD[j] = av_dst[head * HID + quar * 8 + j];
  }
  float pdS[8], pdD[8];
#pragma unroll
  for (int i = 0; i < 8; ++i) {
    float s = 0.f, d = 0.f;
#pragma unroll
    for (int j = 0; j < 8; ++j) { s += acc[i][j] * aS[j]; d += acc[i][j] * aD[j]; }
    pdS[i] = s; pdD[i] = d;
  }
#pragma unroll
  for (int i = 0; i < 8; ++i) {
    pdS[i] += __shfl_xor(pdS[i], 1);  pdD[i] += __shfl_xor(pdD[i], 1);
    pdS[i] += __shfl_xor(pdS[i], 2);  pdD[i] += __shfl_xor(pdD[i], 2);
  }

#pragma unroll
  for (int i = 0; i < 8; ++i) {
    int gr = row0 + r0 + i;
    if (gr < N_NODES) {
      float4* hrow = (float4*)&H[(size_t)gr * HF + c0];
      hrow[0] = make_float4(acc[i][0], acc[i][1], acc[i][2], acc[i][3]);
      hrow[1] = make_float4(acc[i][4], acc[i][5], acc[i][6], acc[i][7]);
      if (quar == 0) {
        AS[gr * HEADS + head] = pdS[i];
        AD[gr * HEADS + head] = pdD[i];
      }
    }
  }
}

// ---------------- global per-head max of AS (overflow bound for softmax) ----
__global__ void k_maxAS(const float* __restrict__ AS, unsigned* __restrict__ M4) {
  __shared__ float4 red[256];
  int t = threadIdx.x;
  float4 v = make_float4(-3.4e38f, -3.4e38f, -3.4e38f, -3.4e38f);
  for (int n = blockIdx.x * 256 + t; n < N_NODES; n += gridDim.x * 256) {
    float4 a = *(const float4*)(AS + 4 * n);
    v.x = fmaxf(v.x, a.x); v.y = fmaxf(v.y, a.y);
    v.z = fmaxf(v.z, a.z); v.w = fmaxf(v.w, a.w);
  }
  red[t] = v; __syncthreads();
  for (int s = 128; s > 0; s >>= 1) {
    if (t < s) {
      float4 o = red[t + s];
      red[t].x = fmaxf(red[t].x, o.x); red[t].y = fmaxf(red[t].y, o.y);
      red[t].z = fmaxf(red[t].z, o.z); red[t].w = fmaxf(red[t].w, o.w);
    }
    __syncthreads();
  }
  if (t == 0) {
    atomicMax(&M4[0], fenc(red[0].x));
    atomicMax(&M4[1], fenc(red[0].y));
    atomicMax(&M4[2], fenc(red[0].z));
    atomicMax(&M4[3], fenc(red[0].w));
  }
}

// ---------------- fused softmax + aggregation ----------------
// Per edge: e = exp(lrelu(as+ad) - m) with m = lrelu(M_h + ad) >= true max;
// accumulate acc += e*h and den += e; normalize at the end. Wave per node,
// half-wave per edge parity, 2x unroll -> 4 gather chains in flight.
template<bool CONCAT>
__global__ void __launch_bounds__(256) k_aggregate(
    const int* __restrict__ rs, const int* __restrict__ csr_src,
    const float* __restrict__ H, const float* __restrict__ AS,
    const float* __restrict__ AD, const unsigned* __restrict__ M4,
    const float* __restrict__ bias, float* __restrict__ OUT) {
  int n = blockIdx.x * 4 + (threadIdx.x >> 6);
  if (n >= N_NODES) return;
  int lane = threadIdx.x & 63;
  int half = lane >> 5;               // edge-slot parity
  int l = lane & 31;
  int c = l * 4;                      // this lane's 4 columns
  int head = l >> 3;
  int b = rs[n], e = rs[n + 1];

  float ad = AD[4 * n + head];
  float m = lrelu(fdec(M4[head]) + ad);

  float ax = 0.f, ay = 0.f, az = 0.f, aw = 0.f, den = 0.f;
  int jj = b + half;
  for (; jj + 2 < e; jj += 4) {       // two edges per step for this half
    int s0 = csr_src[jj];
    int s1 = csr_src[jj + 2];
    float e0 = __expf(lrelu(AS[4 * s0 + head] + ad) - m);
    float e1 = __expf(lrelu(AS[4 * s1 + head] + ad) - m);
    float4 h0 = *(const float4*)&H[(size_t)s0 * HF + c];
    float4 h1 = *(const float4*)&H[(size_t)s1 * HF + c];
    ax += h0.x * e0 + h1.x * e1;
    ay += h0.y * e0 + h1.y * e1;
    az += h0.z * e0 + h1.z * e1;
    aw += h0.w * e0 + h1.w * e1;
    den += e0 + e1;
  }
  if (jj < e) {
    int s0 = csr_src[jj];
    float e0 = __expf(lrelu(AS[4 * s0 + head] + ad) - m);
    float4 h0 = *(const float4*)&H[(size_t)s0 * HF + c];
    ax += h0.x * e0; ay += h0.y * e0; az += h0.z * e0; aw += h0.w * e0;
    den += e0;
  }
  // combine the two halves
  ax += __shfl_xor(ax, 32); ay += __shfl_xor(ay, 32);
  az += __shfl_xor(az, 32); aw += __shfl_xor(aw, 32);
  den += __shfl_xor(den, 32);

  float invd = 1.f / den;
  if (CONCAT) {
    if (half == 0) {
      float4 o;
      o.x = elu_f(ax * invd + bias[c]);
      o.y = elu_f(ay * invd + bias[c + 1]);
      o.z = elu_f(az * invd + bias[c + 2]);
      o.w = elu_f(aw * invd + bias[c + 3]);
      *(float4*)&OUT[(size_t)n * HF + c] = o;
    }
  } else {
    ax *= invd; ay *= invd; az *= invd; aw *= invd;
    ax += __shfl_xor(ax, 8);  ay += __shfl_xor(ay, 8);
    az += __shfl_xor(az, 8);  aw += __shfl_xor(aw, 8);
    ax += __shfl_xor(ax, 16); ay += __shfl_xor(ay, 16);
    az += __shfl_xor(az, 16); aw += __shfl_xor(aw, 16);
    if (lane < 8) {
      int cc = l * 4;                 // 0..28
      float4 o;
      o.x = elu_f(0.25f * ax + bias[cc]);
      o.y = elu_f(0.25f * ay + bias[cc + 1]);
      o.z = elu_f(0.25f * az + bias[cc + 2]);
      o.w = elu_f(0.25f * aw + bias[cc + 3]);
      *(float4*)&OUT[(size_t)n * HID + cc] = o;
    }
  }
}

// ---------------- global mean pool + MLP head (one wave per graph) ----------------
__global__ void __launch_bounds__(64) k_pool_mlp(
    const int* __restrict__ batch, const float* __restrict__ H3,
    const float* __restrict__ Wm1, const float* __restrict__ bm1,
    const float* __restrict__ Wm2, const float* __restrict__ bm2,
    float* __restrict__ OUT) {
  int g = blockIdx.x;
  int t = threadIdx.x;
  __shared__ float pooled[HID];
  int lo = 0, hi = N_NODES;
  while (lo < hi) { int mid = (lo + hi) >> 1; if (batch[mid] < g) lo = mid + 1; else hi = mid; }
  int start = lo;
  hi = N_NODES;
  while (lo < hi) { int mid = (lo + hi) >> 1; if (batch[mid] < g + 1) lo = mid + 1; else hi = mid; }
  int end = lo;
  if (t < HID) {
    float s = 0.f;
    for (int n = start; n < end; ++n) s += H3[(size_t)n * HID + t];
    float cnt = (float)(end - start);
    pooled[t] = s / fmaxf(cnt, 1.f);
  }
  __syncthreads();
  float z = bm1[t];
#pragma unroll
  for (int f = 0; f < HID; ++f) z += pooled[f] * Wm1[f * 64 + t];
  z = fmaxf(z, 0.f);
  float p = z * Wm2[t];
  for (int off = 32; off > 0; off >>= 1) p += __shfl_down(p, off);
  if (t == 0) OUT[g] = p + bm2[0];
}

extern "C" void kernel_launch(void* const* d_in, const int* in_sizes, int n_in,
                              void* d_out, int out_size, void* d_ws, size_t ws_size,
                              hipStream_t stream) {
  const float* x    = (const float*)d_in[0];
  const int*   ei   = (const int*)d_in[1];
  const int*   batch= (const int*)d_in[2];
  const float* W1   = (const float*)d_in[3];
  const float* a1s  = (const float*)d_in[4];
  const float* a1d  = (const float*)d_in[5];
  const float* b1   = (const float*)d_in[6];
  const float* W2   = (const float*)d_in[7];
  const float* a2s  = (const float*)d_in[8];
  const float* a2d  = (const float*)d_in[9];
  const float* b2   = (const float*)d_in[10];
  const float* W3   = (const float*)d_in[11];
  const float* a3s  = (const float*)d_in[12];
  const float* a3d  = (const float*)d_in[13];
  const float* b3   = (const float*)d_in[14];
  const float* Wm1  = (const float*)d_in[15];
  const float* bm1  = (const float*)d_in[16];
  const float* Wm2  = (const float*)d_in[17];
  const float* bm2  = (const float*)d_in[18];
  float* out = (float*)d_out;

  char* p = (char*)d_ws;
  auto take = [&](size_t bytes) { char* r = p; p += (bytes + 255) & ~(size_t)255; return r; };
  float*    bufA  = (float*)take((size_t)N_NODES * HF * 4);
  float*    bufB  = (float*)take((size_t)N_NODES * HF * 4);
  float*    AS    = (float*)take((size_t)N_NODES * HEADS * 4);
  float*    AD    = (float*)take((size_t)N_NODES * HEADS * 4);
  unsigned* M4    = (unsigned*)take(4 * 4);
  int*      deg   = (int*)take((size_t)N_NODES * 4);    // reused as fill counters
  int*      rs    = (int*)take((size_t)(N_NODES + 1) * 4);
  int*      csr   = (int*)take((size_t)ET * 4);
  int*      bsums = (int*)take((size_t)512 * 4);

  const int nb_scan = (N_NODES + 255) / 256;  // 391

  hipMemsetAsync(deg, 0, (size_t)N_NODES * 4, stream);
  k_count<<<(ET + 255) / 256, 256, 0, stream>>>(ei, deg);
  k_scan1<<<nb_scan, 256, 0, stream>>>(deg, rs, bsums);
  k_scan2<<<1, 512, 0, stream>>>(bsums, nb_scan);
  k_scan3<<<nb_scan, 256, 0, stream>>>(rs, bsums);
  hipMemsetAsync(deg, 0, (size_t)N_NODES * 4, stream);
  k_fill<<<(ET + 255) / 256, 256, 0, stream>>>(ei, rs, deg, csr);

  const int gb = (N_NODES + 127) / 128;       // 782 blocks of 128 rows
  const int ab = (N_NODES + 3) / 4;           // aggregate: 4 nodes/block

  // layer 1 (K=64)
  k_gemm_attn<IN_DIM><<<gb, 256, 0, stream>>>(x, W1, a1s, a1d, bufA, AS, AD);
  hipMemsetAsync(M4, 0, 16, stream);
  k_maxAS<<<128, 256, 0, stream>>>(AS, M4);
  k_aggregate<true><<<ab, 256, 0, stream>>>(rs, csr, bufA, AS, AD, M4, b1, bufB);
  // layer 2 (K=128)
  k_gemm_attn<HF><<<gb, 256, 0, stream>>>(bufB, W2, a2s, a2d, bufA, AS, AD);
  hipMemsetAsync(M4, 0, 16, stream);
  k_maxAS<<<128, 256, 0, stream>>>(AS, M4);
  k_aggregate<true><<<ab, 256, 0, stream>>>(rs, csr, bufA, AS, AD, M4, b2, bufB);
  // layer 3 (K=128, concat=False -> head mean)
  k_gemm_attn<HF><<<gb, 256, 0, stream>>>(bufB, W3, a3s, a3d, bufA, AS, AD);
  hipMemsetAsync(M4, 0, 16, stream);
  k_maxAS<<<128, 256, 0, stream>>>(AS, M4);
  k_aggregate<false><<<ab, 256, 0, stream>>>(rs, csr, bufA, AS, AD, M4, b3, bufB);
  // pool + MLP
  k_pool_mlp<<<N_GRAPHS, 64, 0, stream>>>(batch, bufB, Wm1, bm1, Wm2, bm2, out);
}

// Round 6
// 570.204 us; speedup vs baseline: 1.7792x; 1.0243x over previous
//
#include <hip/hip_runtime.h>

#define N_NODES  100000
#define N_EDGES  800000
#define ET       900000   // edges + self loops
#define N_GRAPHS 2000
#define IN_DIM   64
#define HID      32
#define HEADS    4
#define HF       128      // HEADS*HID
#define NEG_SLOPE 0.2f

__device__ __forceinline__ float lrelu(float x) { return x > 0.f ? x : NEG_SLOPE * x; }
__device__ __forceinline__ float elu_f(float x) { return x > 0.f ? x : expm1f(x); }
// order-preserving float<->uint encode for atomicMax over signed floats
__device__ __forceinline__ unsigned fenc(float f) {
  unsigned u = __float_as_uint(f);
  return (u & 0x80000000u) ? ~u : (u | 0x80000000u);
}
__device__ __forceinline__ float fdec(unsigned e) {
  return __uint_as_float((e & 0x80000000u) ? (e ^ 0x80000000u) : ~e);
}

// ---------------- CSR build ----------------
__global__ void k_count(const int* __restrict__ ei, int* __restrict__ deg) {
  int e = blockIdx.x * 256 + threadIdx.x;
  if (e >= ET) return;
  int d = (e < N_EDGES) ? ei[N_EDGES + e] : (e - N_EDGES);
  atomicAdd(&deg[d], 1);
}

__global__ void k_scan1(const int* __restrict__ deg, int* __restrict__ rs, int* __restrict__ bsums) {
  __shared__ int sd[256];
  int t = threadIdx.x;
  int i = blockIdx.x * 256 + t;
  int v = (i < N_NODES) ? deg[i] : 0;
  sd[t] = v; __syncthreads();
  for (int s = 1; s < 256; s <<= 1) {
    int tmp = (t >= s) ? sd[t - s] : 0; __syncthreads();
    sd[t] += tmp; __syncthreads();
  }
  if (i < N_NODES) rs[i] = sd[t] - v;
  if (t == 255) bsums[blockIdx.x] = sd[255];
}

__global__ void k_scan2(int* __restrict__ bsums, int nb) {
  __shared__ int sd[512];
  int t = threadIdx.x;
  int v = (t < nb) ? bsums[t] : 0;
  sd[t] = v; __syncthreads();
  for (int s = 1; s < 512; s <<= 1) {
    int tmp = (t >= s) ? sd[t - s] : 0; __syncthreads();
    sd[t] += tmp; __syncthreads();
  }
  if (t < nb) bsums[t] = sd[t] - v;
}

__global__ void k_scan3(int* __restrict__ rs, const int* __restrict__ bsums) {
  int i = blockIdx.x * 256 + threadIdx.x;
  if (i < N_NODES) rs[i] += bsums[blockIdx.x];
  if (i == 0) rs[N_NODES] = ET;
}

__global__ void k_fill(const int* __restrict__ ei, const int* __restrict__ rs,
                       int* __restrict__ fill, int* __restrict__ csr_src) {
  int e = blockIdx.x * 256 + threadIdx.x;
  if (e >= ET) return;
  int s, d;
  if (e < N_EDGES) { s = ei[e]; d = ei[N_EDGES + e]; }
  else             { s = e - N_EDGES; d = s; }
  int pos = atomicAdd(&fill[d], 1);
  csr_src[rs[d] + pos] = s;
}

// ---------------- GEMM + attention dots (+ fused per-head AS max) ----------
#define XRS 132                        // X^T row stride (floats)
#define WRS 144                        // W k-row stride (floats)
__device__ __forceinline__ int wofs(int c) { return c + 4 * (c >> 5); }

template<int K>
__global__ void __launch_bounds__(256, 4) k_gemm_attn(
    const float* __restrict__ X, const float* __restrict__ Wg,
    const float* __restrict__ av_src, const float* __restrict__ av_dst,
    float* __restrict__ H, float* __restrict__ AS, float* __restrict__ AD,
    unsigned* __restrict__ M4) {
  __shared__ float sXT[32 * XRS];      // [k2][row], 16.9 KB
  __shared__ float sW[32 * WRS];       // [k2][swizzled c], 18.4 KB
  __shared__ unsigned smax[HEADS];
  const int t = threadIdx.x;
  const int tr = t >> 4;               // 0..15
  const int tc = t & 15;               // 0..15
  const int r0 = tr * 8;
  const int c0 = tc * 8;
  const int head = tc >> 2;
  const int quar = tc & 3;
  const int row0 = blockIdx.x * 128;
  const int wbase = wofs(c0);

  if (t < HEADS) smax[t] = 0;          // covered by first loop barrier

  float acc[8][8];
#pragma unroll
  for (int i = 0; i < 8; ++i)
#pragma unroll
    for (int j = 0; j < 8; ++j) acc[i][j] = 0.f;

  for (int kb = 0; kb < K; kb += 32) {
    __syncthreads();
    for (int i = t; i < 128 * 32; i += 256) {
      int kc = i & 31, r = i >> 5;
      int gr = row0 + r;
      sXT[kc * XRS + r] = (gr < N_NODES) ? X[(size_t)gr * K + kb + kc] : 0.f;
    }
    for (int i = t; i < 32 * 128; i += 256) {
      int k2 = i >> 7, c = i & 127;
      sW[k2 * WRS + wofs(c)] = Wg[(size_t)(kb + k2) * HF + c];
    }
    __syncthreads();
#pragma unroll 8
    for (int k2 = 0; k2 < 32; ++k2) {
      float4 x0 = *(const float4*)&sXT[k2 * XRS + r0];
      float4 x1 = *(const float4*)&sXT[k2 * XRS + r0 + 4];
      float4 w0 = *(const float4*)&sW[k2 * WRS + wbase];
      float4 w1 = *(const float4*)&sW[k2 * WRS + wbase + 4];
      float xv[8] = {x0.x, x0.y, x0.z, x0.w, x1.x, x1.y, x1.z, x1.w};
      float wv[8] = {w0.x, w0.y, w0.z, w0.w, w1.x, w1.y, w1.z, w1.w};
#pragma unroll
      for (int i = 0; i < 8; ++i)
#pragma unroll
        for (int j = 0; j < 8; ++j) acc[i][j] += xv[i] * wv[j];
    }
  }

  // epilogue: attention dots (short live range for aS/aD)
  float aS[8], aD[8];
#pragma unroll
  for (int j = 0; j < 8; ++j) {
    aS[j] = av_src[head * HID + quar * 8 + j];
    aD[j] = av_dst[head * HID + quar * 8 + j];
  }
  float pdS[8], pdD[8];
#pragma unroll
  for (int i = 0; i < 8; ++i) {
    float s = 0.f, d = 0.f;
#pragma unroll
    for (int j = 0; j < 8; ++j) { s += acc[i][j] * aS[j]; d += acc[i][j] * aD[j]; }
    pdS[i] = s; pdD[i] = d;
  }
#pragma unroll
  for (int i = 0; i < 8; ++i) {
    pdS[i] += __shfl_xor(pdS[i], 1);  pdD[i] += __shfl_xor(pdD[i], 1);
    pdS[i] += __shfl_xor(pdS[i], 2);  pdD[i] += __shfl_xor(pdD[i], 2);
  }

  float mloc = -3.4e38f;
#pragma unroll
  for (int i = 0; i < 8; ++i) {
    int gr = row0 + r0 + i;
    if (gr < N_NODES) {
      float4* hrow = (float4*)&H[(size_t)gr * HF + c0];
      hrow[0] = make_float4(acc[i][0], acc[i][1], acc[i][2], acc[i][3]);
      hrow[1] = make_float4(acc[i][4], acc[i][5], acc[i][6], acc[i][7]);
      if (quar == 0) {
        AS[gr * HEADS + head] = pdS[i];
        AD[gr * HEADS + head] = pdD[i];
        mloc = fmaxf(mloc, pdS[i]);
      }
    }
  }
  // fused per-head max of AS -> M4 (block LDS reduce, then global atomic)
  if (quar == 0) atomicMax(&smax[head], fenc(mloc));
  __syncthreads();
  if (t < HEADS) atomicMax(&M4[t], smax[t]);
}

// ---------------- fused softmax + aggregation (chunk-preloaded) ----------
// Wave per node. Preload chunk of <=64 edges: coalesced csr load, one AS
// gather + exp per edge (all 4 heads), weights to wave-private LDS. FMA loop:
// s via bpermute, w via ds_read; H gathers have no load->load dependence.
template<bool CONCAT>
__global__ void __launch_bounds__(256) k_aggregate(
    const int* __restrict__ rs, const int* __restrict__ csr_src,
    const float* __restrict__ H, const float* __restrict__ AS,
    const float* __restrict__ AD, const unsigned* __restrict__ M4,
    const float* __restrict__ bias, float* __restrict__ OUT) {
  __shared__ float sW4[4][256];        // [wave][edge*4+head]
  int wv = threadIdx.x >> 6;
  int n = blockIdx.x * 4 + wv;
  if (n >= N_NODES) return;
  int lane = threadIdx.x & 63;
  int half = lane >> 5;
  int l = lane & 31;
  int c = l * 4;                       // this lane's 4 columns
  int head = l >> 3;
  int b = rs[n], e = rs[n + 1];
  int deg = e - b;

  float4 ad4 = *(const float4*)(AD + 4 * n);
  float4 m4;
  m4.x = lrelu(fdec(M4[0]) + ad4.x);
  m4.y = lrelu(fdec(M4[1]) + ad4.y);
  m4.z = lrelu(fdec(M4[2]) + ad4.z);
  m4.w = lrelu(fdec(M4[3]) + ad4.w);

  float ax = 0.f, ay = 0.f, az = 0.f, aw = 0.f, den = 0.f;

  for (int cb = 0; cb < deg; cb += 64) {
    int nchunk = min(64, deg - cb);
    int s_l = 0;
    float4 w4 = make_float4(0.f, 0.f, 0.f, 0.f);
    if (lane < nchunk) {
      s_l = csr_src[b + cb + lane];
      float4 as4 = *(const float4*)(AS + 4 * s_l);
      w4.x = __expf(lrelu(as4.x + ad4.x) - m4.x);
      w4.y = __expf(lrelu(as4.y + ad4.y) - m4.y);
      w4.z = __expf(lrelu(as4.z + ad4.z) - m4.z);
      w4.w = __expf(lrelu(as4.w + ad4.w) - m4.w);
    }
    *(float4*)&sW4[wv][lane * 4] = w4;
    asm volatile("" ::: "memory");     // keep ds_write before ds_reads below

    for (int j = 0; j < nchunk; j += 4) {
      int slA = j + half;              // edges j, j+1 across the two halves
      int slB = j + 2 + half;          // edges j+2, j+3
      int sA = __shfl(s_l, slA);
      int sB = __shfl(s_l, slB);
      float wA = sW4[wv][((slA & 63) << 2) + head];
      float wB = sW4[wv][((slB & 63) << 2) + head];
      if (slA < nchunk) {
        float4 h = *(const float4*)&H[(size_t)sA * HF + c];
        ax += h.x * wA; ay += h.y * wA; az += h.z * wA; aw += h.w * wA;
        den += wA;
      }
      if (slB < nchunk) {
        float4 h = *(const float4*)&H[(size_t)sB * HF + c];
        ax += h.x * wB; ay += h.y * wB; az += h.z * wB; aw += h.w * wB;
        den += wB;
      }
    }
  }
  // each lane summed its half's edges for its own head; fold halves
  ax += __shfl_xor(ax, 32); ay += __shfl_xor(ay, 32);
  az += __shfl_xor(az, 32); aw += __shfl_xor(aw, 32);
  den += __shfl_xor(den, 32);

  float invd = 1.f / den;
  if (CONCAT) {
    if (half == 0) {
      float4 o;
      o.x = elu_f(ax * invd + bias[c]);
      o.y = elu_f(ay * invd + bias[c + 1]);
      o.z = elu_f(az * invd + bias[c + 2]);
      o.w = elu_f(aw * invd + bias[c + 3]);
      *(float4*)&OUT[(size_t)n * HF + c] = o;
    }
  } else {
    ax *= invd; ay *= invd; az *= invd; aw *= invd;
    ax += __shfl_xor(ax, 8);  ay += __shfl_xor(ay, 8);
    az += __shfl_xor(az, 8);  aw += __shfl_xor(aw, 8);
    ax += __shfl_xor(ax, 16); ay += __shfl_xor(ay, 16);
    az += __shfl_xor(az, 16); aw += __shfl_xor(aw, 16);
    if (lane < 8) {
      int cc = l * 4;                  // 0..28
      float4 o;
      o.x = elu_f(0.25f * ax + bias[cc]);
      o.y = elu_f(0.25f * ay + bias[cc + 1]);
      o.z = elu_f(0.25f * az + bias[cc + 2]);
      o.w = elu_f(0.25f * aw + bias[cc + 3]);
      *(float4*)&OUT[(size_t)n * HID + cc] = o;
    }
  }
}

// ---------------- global mean pool + MLP head (one wave per graph) ----------------
__global__ void __launch_bounds__(64) k_pool_mlp(
    const int* __restrict__ batch, const float* __restrict__ H3,
    const float* __restrict__ Wm1, const float* __restrict__ bm1,
    const float* __restrict__ Wm2, const float* __restrict__ bm2,
    float* __restrict__ OUT) {
  int g = blockIdx.x;
  int t = threadIdx.x;
  __shared__ float pooled[HID];
  int lo = 0, hi = N_NODES;
  while (lo < hi) { int mid = (lo + hi) >> 1; if (batch[mid] < g) lo = mid + 1; else hi = mid; }
  int start = lo;
  hi = N_NODES;
  while (lo < hi) { int mid = (lo + hi) >> 1; if (batch[mid] < g + 1) lo = mid + 1; else hi = mid; }
  int end = lo;
  if (t < HID) {
    float s = 0.f;
    for (int n = start; n < end; ++n) s += H3[(size_t)n * HID + t];
    float cnt = (float)(end - start);
    pooled[t] = s / fmaxf(cnt, 1.f);
  }
  __syncthreads();
  float z = bm1[t];
#pragma unroll
  for (int f = 0; f < HID; ++f) z += pooled[f] * Wm1[f * 64 + t];
  z = fmaxf(z, 0.f);
  float p = z * Wm2[t];
  for (int off = 32; off > 0; off >>= 1) p += __shfl_down(p, off);
  if (t == 0) OUT[g] = p + bm2[0];
}

extern "C" void kernel_launch(void* const* d_in, const int* in_sizes, int n_in,
                              void* d_out, int out_size, void* d_ws, size_t ws_size,
                              hipStream_t stream) {
  const float* x    = (const float*)d_in[0];
  const int*   ei   = (const int*)d_in[1];
  const int*   batch= (const int*)d_in[2];
  const float* W1   = (const float*)d_in[3];
  const float* a1s  = (const float*)d_in[4];
  const float* a1d  = (const float*)d_in[5];
  const float* b1   = (const float*)d_in[6];
  const float* W2   = (const float*)d_in[7];
  const float* a2s  = (const float*)d_in[8];
  const float* a2d  = (const float*)d_in[9];
  const float* b2   = (const float*)d_in[10];
  const float* W3   = (const float*)d_in[11];
  const float* a3s  = (const float*)d_in[12];
  const float* a3d  = (const float*)d_in[13];
  const float* b3   = (const float*)d_in[14];
  const float* Wm1  = (const float*)d_in[15];
  const float* bm1  = (const float*)d_in[16];
  const float* Wm2  = (const float*)d_in[17];
  const float* bm2  = (const float*)d_in[18];
  float* out = (float*)d_out;

  char* p = (char*)d_ws;
  auto take = [&](size_t bytes) { char* r = p; p += (bytes + 255) & ~(size_t)255; return r; };
  float*    bufA  = (float*)take((size_t)N_NODES * HF * 4);
  float*    bufB  = (float*)take((size_t)N_NODES * HF * 4);
  float*    AS    = (float*)take((size_t)N_NODES * HEADS * 4);
  float*    AD    = (float*)take((size_t)N_NODES * HEADS * 4);
  unsigned* M4    = (unsigned*)take(3 * 4 * 4);         // 3 layers x 4 heads
  int*      deg   = (int*)take((size_t)N_NODES * 4);    // reused as fill counters
  int*      rs    = (int*)take((size_t)(N_NODES + 1) * 4);
  int*      csr   = (int*)take((size_t)ET * 4);
  int*      bsums = (int*)take((size_t)512 * 4);

  unsigned* M4a = M4;
  unsigned* M4b = M4 + 4;
  unsigned* M4c = M4 + 8;

  const int nb_scan = (N_NODES + 255) / 256;  // 391

  hipMemsetAsync(deg, 0, (size_t)N_NODES * 4, stream);
  hipMemsetAsync(M4, 0, 48, stream);
  k_count<<<(ET + 255) / 256, 256, 0, stream>>>(ei, deg);
  k_scan1<<<nb_scan, 256, 0, stream>>>(deg, rs, bsums);
  k_scan2<<<1, 512, 0, stream>>>(bsums, nb_scan);
  k_scan3<<<nb_scan, 256, 0, stream>>>(rs, bsums);
  hipMemsetAsync(deg, 0, (size_t)N_NODES * 4, stream);
  k_fill<<<(ET + 255) / 256, 256, 0, stream>>>(ei, rs, deg, csr);

  const int gb = (N_NODES + 127) / 128;       // 782 blocks of 128 rows
  const int ab = (N_NODES + 3) / 4;           // aggregate: 4 nodes/block

  // layer 1 (K=64)
  k_gemm_attn<IN_DIM><<<gb, 256, 0, stream>>>(x, W1, a1s, a1d, bufA, AS, AD, M4a);
  k_aggregate<true><<<ab, 256, 0, stream>>>(rs, csr, bufA, AS, AD, M4a, b1, bufB);
  // layer 2 (K=128)
  k_gemm_attn<HF><<<gb, 256, 0, stream>>>(bufB, W2, a2s, a2d, bufA, AS, AD, M4b);
  k_aggregate<true><<<ab, 256, 0, stream>>>(rs, csr, bufA, AS, AD, M4b, b2, bufB);
  // layer 3 (K=128, concat=False -> head mean)
  k_gemm_attn<HF><<<gb, 256, 0, stream>>>(bufB, W3, a3s, a3d, bufA, AS, AD, M4c);
  k_aggregate<false><<<ab, 256, 0, stream>>>(rs, csr, bufA, AS, AD, M4c, b3, bufB);
  // pool + MLP
  k_pool_mlp<<<N_GRAPHS, 64, 0, stream>>>(batch, bufB, Wm1, bm1, Wm2, bm2, out);
}

// Round 7
// 548.927 us; speedup vs baseline: 1.8481x; 1.0388x over previous
//
#include <hip/hip_runtime.h>

#define N_NODES  100000
#define N_EDGES  800000
#define ET       900000   // edges + self loops
#define N_GRAPHS 2000
#define IN_DIM   64
#define HID      32
#define HEADS    4
#define HF       128      // HEADS*HID
#define NEG_SLOPE 0.2f

__device__ __forceinline__ float lrelu(float x) { return x > 0.f ? x : NEG_SLOPE * x; }
__device__ __forceinline__ float elu_f(float x) { return x > 0.f ? x : expm1f(x); }
// order-preserving float<->uint encode for atomicMax over signed floats
__device__ __forceinline__ unsigned fenc(float f) {
  unsigned u = __float_as_uint(f);
  return (u & 0x80000000u) ? ~u : (u | 0x80000000u);
}
__device__ __forceinline__ float fdec(unsigned e) {
  return __uint_as_float((e & 0x80000000u) ? (e ^ 0x80000000u) : ~e);
}

// ---------------- CSR build ----------------
__global__ void k_count(const int* __restrict__ ei, int* __restrict__ deg) {
  int e = blockIdx.x * 256 + threadIdx.x;
  if (e >= ET) return;
  int d = (e < N_EDGES) ? ei[N_EDGES + e] : (e - N_EDGES);
  atomicAdd(&deg[d], 1);
}

__global__ void k_scan1(const int* __restrict__ deg, int* __restrict__ rs, int* __restrict__ bsums) {
  __shared__ int sd[256];
  int t = threadIdx.x;
  int i = blockIdx.x * 256 + t;
  int v = (i < N_NODES) ? deg[i] : 0;
  sd[t] = v; __syncthreads();
  for (int s = 1; s < 256; s <<= 1) {
    int tmp = (t >= s) ? sd[t - s] : 0; __syncthreads();
    sd[t] += tmp; __syncthreads();
  }
  if (i < N_NODES) rs[i] = sd[t] - v;
  if (t == 255) bsums[blockIdx.x] = sd[255];
}

__global__ void k_scan2(int* __restrict__ bsums, int nb) {
  __shared__ int sd[512];
  int t = threadIdx.x;
  int v = (t < nb) ? bsums[t] : 0;
  sd[t] = v; __syncthreads();
  for (int s = 1; s < 512; s <<= 1) {
    int tmp = (t >= s) ? sd[t - s] : 0; __syncthreads();
    sd[t] += tmp; __syncthreads();
  }
  if (t < nb) bsums[t] = sd[t] - v;
}

__global__ void k_scan3(int* __restrict__ rs, const int* __restrict__ bsums) {
  int i = blockIdx.x * 256 + threadIdx.x;
  if (i < N_NODES) rs[i] += bsums[blockIdx.x];
  if (i == 0) rs[N_NODES] = ET;
}

__global__ void k_fill(const int* __restrict__ ei, const int* __restrict__ rs,
                       int* __restrict__ fill, int* __restrict__ csr_src) {
  int e = blockIdx.x * 256 + threadIdx.x;
  if (e >= ET) return;
  int s, d;
  if (e < N_EDGES) { s = ei[e]; d = ei[N_EDGES + e]; }
  else             { s = e - N_EDGES; d = s; }
  int pos = atomicAdd(&fill[d], 1);
  csr_src[rs[d] + pos] = s;
}

// ---------------- GEMM + attention dots (+ fused per-head AS max) ----------
#define XRS 132                        // X^T row stride (floats)
#define WRS 144                        // W k-row stride (floats)
__device__ __forceinline__ int wofs(int c) { return c + 4 * (c >> 5); }

template<int K>
__global__ void __launch_bounds__(256, 4) k_gemm_attn(
    const float* __restrict__ X, const float* __restrict__ Wg,
    const float* __restrict__ av_src, const float* __restrict__ av_dst,
    float* __restrict__ H, float* __restrict__ AS, float* __restrict__ AD,
    unsigned* __restrict__ M4) {
  __shared__ float sXT[32 * XRS];      // [k2][row], 16.9 KB
  __shared__ float sW[32 * WRS];       // [k2][swizzled c], 18.4 KB
  __shared__ unsigned smax[HEADS];
  const int t = threadIdx.x;
  const int tr = t >> 4;               // 0..15
  const int tc = t & 15;               // 0..15
  const int r0 = tr * 8;
  const int c0 = tc * 8;
  const int head = tc >> 2;
  const int quar = tc & 3;
  const int row0 = blockIdx.x * 128;
  const int wbase = wofs(c0);

  if (t < HEADS) smax[t] = 0;          // covered by first loop barrier

  float acc[8][8];
#pragma unroll
  for (int i = 0; i < 8; ++i)
#pragma unroll
    for (int j = 0; j < 8; ++j) acc[i][j] = 0.f;

  for (int kb = 0; kb < K; kb += 32) {
    __syncthreads();
    for (int i = t; i < 128 * 32; i += 256) {
      int kc = i & 31, r = i >> 5;
      int gr = row0 + r;
      sXT[kc * XRS + r] = (gr < N_NODES) ? X[(size_t)gr * K + kb + kc] : 0.f;
    }
    for (int i = t; i < 32 * 128; i += 256) {
      int k2 = i >> 7, c = i & 127;
      sW[k2 * WRS + wofs(c)] = Wg[(size_t)(kb + k2) * HF + c];
    }
    __syncthreads();
#pragma unroll 8
    for (int k2 = 0; k2 < 32; ++k2) {
      float4 x0 = *(const float4*)&sXT[k2 * XRS + r0];
      float4 x1 = *(const float4*)&sXT[k2 * XRS + r0 + 4];
      float4 w0 = *(const float4*)&sW[k2 * WRS + wbase];
      float4 w1 = *(const float4*)&sW[k2 * WRS + wbase + 4];
      float xv[8] = {x0.x, x0.y, x0.z, x0.w, x1.x, x1.y, x1.z, x1.w};
      float wv[8] = {w0.x, w0.y, w0.z, w0.w, w1.x, w1.y, w1.z, w1.w};
#pragma unroll
      for (int i = 0; i < 8; ++i)
#pragma unroll
        for (int j = 0; j < 8; ++j) acc[i][j] += xv[i] * wv[j];
    }
  }

  // epilogue: attention dots (short live range for aS/aD)
  float aS[8], aD[8];
#pragma unroll
  for (int j = 0; j < 8; ++j) {
    aS[j] = av_src[head * HID + quar * 8 + j];
    aD[j] = av_dst[head * HID + quar * 8 + j];
  }
  float pdS[8], pdD[8];
#pragma unroll
  for (int i = 0; i < 8; ++i) {
    float s = 0.f, d = 0.f;
#pragma unroll
    for (int j = 0; j < 8; ++j) { s += acc[i][j] * aS[j]; d += acc[i][j] * aD[j]; }
    pdS[i] = s; pdD[i] = d;
  }
#pragma unroll
  for (int i = 0; i < 8; ++i) {
    pdS[i] += __shfl_xor(pdS[i], 1);  pdD[i] += __shfl_xor(pdD[i], 1);
    pdS[i] += __shfl_xor(pdS[i], 2);  pdD[i] += __shfl_xor(pdD[i], 2);
  }

  float mloc = -3.4e38f;
#pragma unroll
  for (int i = 0; i < 8; ++i) {
    int gr = row0 + r0 + i;
    if (gr < N_NODES) {
      float4* hrow = (float4*)&H[(size_t)gr * HF + c0];
      hrow[0] = make_float4(acc[i][0], acc[i][1], acc[i][2], acc[i][3]);
      hrow[1] = make_float4(acc[i][4], acc[i][5], acc[i][6], acc[i][7]);
      if (quar == 0) {
        AS[gr * HEADS + head] = pdS[i];
        AD[gr * HEADS + head] = pdD[i];
        mloc = fmaxf(mloc, pdS[i]);
      }
    }
  }
  // fused per-head max of AS -> M4 (block LDS reduce, then global atomic)
  if (quar == 0) atomicMax(&smax[head], fenc(mloc));
  __syncthreads();
  if (t < HEADS) atomicMax(&M4[t], smax[t]);
}

// ---------------- fused softmax + aggregation ----------------
// Half-wave (32 lanes) per node: each lane owns 4 columns (float4) of the
// 512B H row. 4 edges unrolled -> 8 independent csr->H gather chains per
// wave. Every lane accumulates the full denominator (no shuffles in the
// CONCAT path). e = exp(lrelu(as+ad) - m), m = lrelu(M_h + ad) >= true max.
template<bool CONCAT>
__global__ void __launch_bounds__(256) k_aggregate(
    const int* __restrict__ rs, const int* __restrict__ csr_src,
    const float* __restrict__ H, const float* __restrict__ AS,
    const float* __restrict__ AD, const unsigned* __restrict__ M4,
    const float* __restrict__ bias, float* __restrict__ OUT) {
  int n = blockIdx.x * 8 + (threadIdx.x >> 5);
  if (n >= N_NODES) return;
  int sl = threadIdx.x & 31;
  int c = sl * 4;                      // this lane's 4 columns
  int head = sl >> 3;
  int b = rs[n], e = rs[n + 1];

  float ad = AD[4 * n + head];
  float m = lrelu(fdec(M4[head]) + ad);

  float ax = 0.f, ay = 0.f, az = 0.f, aw = 0.f, den = 0.f;
  int jj = b;
  for (; jj + 3 < e; jj += 4) {        // 4 gather chains in flight
    int s0 = csr_src[jj];
    int s1 = csr_src[jj + 1];
    int s2 = csr_src[jj + 2];
    int s3 = csr_src[jj + 3];
    float e0 = __expf(lrelu(AS[4 * s0 + head] + ad) - m);
    float e1 = __expf(lrelu(AS[4 * s1 + head] + ad) - m);
    float e2 = __expf(lrelu(AS[4 * s2 + head] + ad) - m);
    float e3 = __expf(lrelu(AS[4 * s3 + head] + ad) - m);
    float4 h0 = *(const float4*)&H[(size_t)s0 * HF + c];
    float4 h1 = *(const float4*)&H[(size_t)s1 * HF + c];
    float4 h2 = *(const float4*)&H[(size_t)s2 * HF + c];
    float4 h3 = *(const float4*)&H[(size_t)s3 * HF + c];
    ax += h0.x * e0 + h1.x * e1 + h2.x * e2 + h3.x * e3;
    ay += h0.y * e0 + h1.y * e1 + h2.y * e2 + h3.y * e3;
    az += h0.z * e0 + h1.z * e1 + h2.z * e2 + h3.z * e3;
    aw += h0.w * e0 + h1.w * e1 + h2.w * e2 + h3.w * e3;
    den += (e0 + e1) + (e2 + e3);
  }
  for (; jj < e; ++jj) {
    int s0 = csr_src[jj];
    float e0 = __expf(lrelu(AS[4 * s0 + head] + ad) - m);
    float4 h0 = *(const float4*)&H[(size_t)s0 * HF + c];
    ax += h0.x * e0; ay += h0.y * e0; az += h0.z * e0; aw += h0.w * e0;
    den += e0;
  }

  float invd = 1.f / den;
  if (CONCAT) {
    float4 o;
    o.x = elu_f(ax * invd + bias[c]);
    o.y = elu_f(ay * invd + bias[c + 1]);
    o.z = elu_f(az * invd + bias[c + 2]);
    o.w = elu_f(aw * invd + bias[c + 3]);
    *(float4*)&OUT[(size_t)n * HF + c] = o;
  } else {
    // mean over heads: fold lanes sl^8, sl^16 (stay within the 32-lane half)
    ax *= invd; ay *= invd; az *= invd; aw *= invd;
    ax += __shfl_xor(ax, 8);  ay += __shfl_xor(ay, 8);
    az += __shfl_xor(az, 8);  aw += __shfl_xor(aw, 8);
    ax += __shfl_xor(ax, 16); ay += __shfl_xor(ay, 16);
    az += __shfl_xor(az, 16); aw += __shfl_xor(aw, 16);
    if (sl < 8) {
      int cc = sl * 4;                 // 0..28
      float4 o;
      o.x = elu_f(0.25f * ax + bias[cc]);
      o.y = elu_f(0.25f * ay + bias[cc + 1]);
      o.z = elu_f(0.25f * az + bias[cc + 2]);
      o.w = elu_f(0.25f * aw + bias[cc + 3]);
      *(float4*)&OUT[(size_t)n * HID + cc] = o;
    }
  }
}

// ---------------- global mean pool + MLP head (one wave per graph) ----------------
__global__ void __launch_bounds__(64) k_pool_mlp(
    const int* __restrict__ batch, const float* __restrict__ H3,
    const float* __restrict__ Wm1, const float* __restrict__ bm1,
    const float* __restrict__ Wm2, const float* __restrict__ bm2,
    float* __restrict__ OUT) {
  int g = blockIdx.x;
  int t = threadIdx.x;
  __shared__ float pooled[HID];
  int lo = 0, hi = N_NODES;
  while (lo < hi) { int mid = (lo + hi) >> 1; if (batch[mid] < g) lo = mid + 1; else hi = mid; }
  int start = lo;
  hi = N_NODES;
  while (lo < hi) { int mid = (lo + hi) >> 1; if (batch[mid] < g + 1) lo = mid + 1; else hi = mid; }
  int end = lo;
  if (t < HID) {
    float s = 0.f;
    for (int n = start; n < end; ++n) s += H3[(size_t)n * HID + t];
    float cnt = (float)(end - start);
    pooled[t] = s / fmaxf(cnt, 1.f);
  }
  __syncthreads();
  float z = bm1[t];
#pragma unroll
  for (int f = 0; f < HID; ++f) z += pooled[f] * Wm1[f * 64 + t];
  z = fmaxf(z, 0.f);
  float p = z * Wm2[t];
  for (int off = 32; off > 0; off >>= 1) p += __shfl_down(p, off);
  if (t == 0) OUT[g] = p + bm2[0];
}

extern "C" void kernel_launch(void* const* d_in, const int* in_sizes, int n_in,
                              void* d_out, int out_size, void* d_ws, size_t ws_size,
                              hipStream_t stream) {
  const float* x    = (const float*)d_in[0];
  const int*   ei   = (const int*)d_in[1];
  const int*   batch= (const int*)d_in[2];
  const float* W1   = (const float*)d_in[3];
  const float* a1s  = (const float*)d_in[4];
  const float* a1d  = (const float*)d_in[5];
  const float* b1   = (const float*)d_in[6];
  const float* W2   = (const float*)d_in[7];
  const float* a2s  = (const float*)d_in[8];
  const float* a2d  = (const float*)d_in[9];
  const float* b2   = (const float*)d_in[10];
  const float* W3   = (const float*)d_in[11];
  const float* a3s  = (const float*)d_in[12];
  const float* a3d  = (const float*)d_in[13];
  const float* b3   = (const float*)d_in[14];
  const float* Wm1  = (const float*)d_in[15];
  const float* bm1  = (const float*)d_in[16];
  const float* Wm2  = (const float*)d_in[17];
  const float* bm2  = (const float*)d_in[18];
  float* out = (float*)d_out;

  char* p = (char*)d_ws;
  auto take = [&](size_t bytes) { char* r = p; p += (bytes + 255) & ~(size_t)255; return r; };
  float*    bufA  = (float*)take((size_t)N_NODES * HF * 4);
  float*    bufB  = (float*)take((size_t)N_NODES * HF * 4);
  float*    AS    = (float*)take((size_t)N_NODES * HEADS * 4);
  float*    AD    = (float*)take((size_t)N_NODES * HEADS * 4);
  unsigned* M4    = (unsigned*)take(3 * 4 * 4);         // 3 layers x 4 heads
  int*      deg   = (int*)take((size_t)N_NODES * 4);    // reused as fill counters
  int*      rs    = (int*)take((size_t)(N_NODES + 1) * 4);
  int*      csr   = (int*)take((size_t)ET * 4);
  int*      bsums = (int*)take((size_t)512 * 4);

  unsigned* M4a = M4;
  unsigned* M4b = M4 + 4;
  unsigned* M4c = M4 + 8;

  const int nb_scan = (N_NODES + 255) / 256;  // 391

  hipMemsetAsync(deg, 0, (size_t)N_NODES * 4, stream);
  hipMemsetAsync(M4, 0, 48, stream);
  k_count<<<(ET + 255) / 256, 256, 0, stream>>>(ei, deg);
  k_scan1<<<nb_scan, 256, 0, stream>>>(deg, rs, bsums);
  k_scan2<<<1, 512, 0, stream>>>(bsums, nb_scan);
  k_scan3<<<nb_scan, 256, 0, stream>>>(rs, bsums);
  hipMemsetAsync(deg, 0, (size_t)N_NODES * 4, stream);
  k_fill<<<(ET + 255) / 256, 256, 0, stream>>>(ei, rs, deg, csr);

  const int gb = (N_NODES + 127) / 128;       // 782 blocks of 128 rows
  const int ab = (N_NODES + 7) / 8;           // aggregate: 8 nodes/block

  // layer 1 (K=64)
  k_gemm_attn<IN_DIM><<<gb, 256, 0, stream>>>(x, W1, a1s, a1d, bufA, AS, AD, M4a);
  k_aggregate<true><<<ab, 256, 0, stream>>>(rs, csr, bufA, AS, AD, M4a, b1, bufB);
  // layer 2 (K=128)
  k_gemm_attn<HF><<<gb, 256, 0, stream>>>(bufB, W2, a2s, a2d, bufA, AS, AD, M4b);
  k_aggregate<true><<<ab, 256, 0, stream>>>(rs, csr, bufA, AS, AD, M4b, b2, bufB);
  // layer 3 (K=128, concat=False -> head mean)
  k_gemm_attn<HF><<<gb, 256, 0, stream>>>(bufB, W3, a3s, a3d, bufA, AS, AD, M4c);
  k_aggregate<false><<<ab, 256, 0, stream>>>(rs, csr, bufA, AS, AD, M4c, b3, bufB);
  // pool + MLP
  k_pool_mlp<<<N_GRAPHS, 64, 0, stream>>>(batch, bufB, Wm1, bm1, Wm2, bm2, out);
}

// Round 8
// 527.442 us; speedup vs baseline: 1.9234x; 1.0407x over previous
//
#include <hip/hip_runtime.h>

#define N_NODES  100000
#define N_EDGES  800000
#define ET       900000   // edges + self loops
#define N_GRAPHS 2000
#define IN_DIM   64
#define HID      32
#define HEADS    4
#define HF       128      // HEADS*HID
#define NEG_SLOPE 0.2f

__device__ __forceinline__ float lrelu(float x) { return x > 0.f ? x : NEG_SLOPE * x; }
__device__ __forceinline__ float elu_f(float x) { return x > 0.f ? x : expm1f(x); }
// order-preserving float<->uint encode for atomicMax over signed floats
__device__ __forceinline__ unsigned fenc(float f) {
  unsigned u = __float_as_uint(f);
  return (u & 0x80000000u) ? ~u : (u | 0x80000000u);
}
__device__ __forceinline__ float fdec(unsigned e) {
  return __uint_as_float((e & 0x80000000u) ? (e ^ 0x80000000u) : ~e);
}

// ---------------- CSR build ----------------
__global__ void k_count(const int* __restrict__ ei, int* __restrict__ deg) {
  int e = blockIdx.x * 256 + threadIdx.x;
  if (e >= ET) return;
  int d = (e < N_EDGES) ? ei[N_EDGES + e] : (e - N_EDGES);
  atomicAdd(&deg[d], 1);
}

__global__ void k_scan1(const int* __restrict__ deg, int* __restrict__ rs, int* __restrict__ bsums) {
  __shared__ int sd[256];
  int t = threadIdx.x;
  int i = blockIdx.x * 256 + t;
  int v = (i < N_NODES) ? deg[i] : 0;
  sd[t] = v; __syncthreads();
  for (int s = 1; s < 256; s <<= 1) {
    int tmp = (t >= s) ? sd[t - s] : 0; __syncthreads();
    sd[t] += tmp; __syncthreads();
  }
  if (i < N_NODES) rs[i] = sd[t] - v;
  if (t == 255) bsums[blockIdx.x] = sd[255];
}

__global__ void k_scan2(int* __restrict__ bsums, int nb) {
  __shared__ int sd[512];
  int t = threadIdx.x;
  int v = (t < nb) ? bsums[t] : 0;
  sd[t] = v; __syncthreads();
  for (int s = 1; s < 512; s <<= 1) {
    int tmp = (t >= s) ? sd[t - s] : 0; __syncthreads();
    sd[t] += tmp; __syncthreads();
  }
  if (t < nb) bsums[t] = sd[t] - v;
}

__global__ void k_scan3(int* __restrict__ rs, const int* __restrict__ bsums) {
  int i = blockIdx.x * 256 + threadIdx.x;
  if (i < N_NODES) rs[i] += bsums[blockIdx.x];
  if (i == 0) rs[N_NODES] = ET;
}

__global__ void k_fill(const int* __restrict__ ei, const int* __restrict__ rs,
                       int* __restrict__ fill, int* __restrict__ csr_src) {
  int e = blockIdx.x * 256 + threadIdx.x;
  if (e >= ET) return;
  int s, d;
  if (e < N_EDGES) { s = ei[e]; d = ei[N_EDGES + e]; }
  else             { s = e - N_EDGES; d = s; }
  int pos = atomicAdd(&fill[d], 1);
  csr_src[rs[d] + pos] = s;
}

// ---------------- GEMM + attention dots (reg-prefetch double-buffered) -----
// Per 32-k chunk: barrier -> ds_write prefetched regs -> issue next chunk's
// global loads (latency hides under compute) -> barrier -> compute.
#define XRS 132                        // X^T row stride (floats)
#define WRS 144                        // W k-row stride (floats)
__device__ __forceinline__ int wofs(int c) { return c + 4 * (c >> 5); }

template<int K>
__global__ void __launch_bounds__(256, 3) k_gemm_attn(
    const float* __restrict__ X, const float* __restrict__ Wg,
    const float* __restrict__ av_src, const float* __restrict__ av_dst,
    float* __restrict__ H, float* __restrict__ AS, float* __restrict__ AD,
    unsigned* __restrict__ M4) {
  __shared__ float sXT[32 * XRS];      // [k2][row], 16.9 KB
  __shared__ float sW[32 * WRS];       // [k2][swizzled c], 18.4 KB
  __shared__ unsigned smax[HEADS];
  const int t = threadIdx.x;
  const int tr = t >> 4;               // 0..15
  const int tc = t & 15;               // 0..15
  const int r0 = tr * 8;
  const int c0 = tc * 8;
  const int head = tc >> 2;
  const int quar = tc & 3;
  const int row0 = blockIdx.x * 128;
  const int wbase = wofs(c0);

  if (t < HEADS) smax[t] = 0;          // covered by first barrier

  // staging geometry (per 32-k chunk, 4 float4 passes each for X and W)
  const int xr = t >> 3;               // row 0..31 (+32 per pass)
  const int xk = (t & 7) * 4;          // k-quad within chunk
  const int wk = t >> 5;               // k2 0..7 (+8 per pass)
  const int wc = (t & 31) * 4;         // col-quad
  const int wdst = wofs(wc);           // swizzled (quad stays contiguous)

  float4 xreg[4], wreg[4];
#define LOADREGS(kb)                                                           \
  {                                                                            \
    _Pragma("unroll")                                                          \
    for (int p = 0; p < 4; ++p) {                                              \
      int gr = row0 + xr + 32 * p;                                             \
      xreg[p] = (gr < N_NODES)                                                 \
          ? *(const float4*)&X[(size_t)gr * K + (kb) + xk]                     \
          : make_float4(0.f, 0.f, 0.f, 0.f);                                   \
      wreg[p] = *(const float4*)&Wg[(size_t)((kb) + wk + 8 * p) * HF + wc];    \
    }                                                                          \
  }
#define STOREREGS()                                                            \
  {                                                                            \
    _Pragma("unroll")                                                          \
    for (int p = 0; p < 4; ++p) {                                              \
      int rr = xr + 32 * p;                                                    \
      sXT[(xk + 0) * XRS + rr] = xreg[p].x;                                    \
      sXT[(xk + 1) * XRS + rr] = xreg[p].y;                                    \
      sXT[(xk + 2) * XRS + rr] = xreg[p].z;                                    \
      sXT[(xk + 3) * XRS + rr] = xreg[p].w;                                    \
      *(float4*)&sW[(wk + 8 * p) * WRS + wdst] = wreg[p];                      \
    }                                                                          \
  }

  float acc[8][8];
#pragma unroll
  for (int i = 0; i < 8; ++i)
#pragma unroll
    for (int j = 0; j < 8; ++j) acc[i][j] = 0.f;

  LOADREGS(0);
  for (int kb = 0; kb < K; kb += 32) {
    __syncthreads();                   // previous compute done; LDS writable
    STOREREGS();
    if (kb + 32 < K) LOADREGS(kb + 32);  // issue early; completes under compute
    __syncthreads();                   // LDS ready
#pragma unroll 8
    for (int k2 = 0; k2 < 32; ++k2) {
      float4 x0 = *(const float4*)&sXT[k2 * XRS + r0];
      float4 x1 = *(const float4*)&sXT[k2 * XRS + r0 + 4];
      float4 w0 = *(const float4*)&sW[k2 * WRS + wbase];
      float4 w1 = *(const float4*)&sW[k2 * WRS + wbase + 4];
      float xv[8] = {x0.x, x0.y, x0.z, x0.w, x1.x, x1.y, x1.z, x1.w};
      float wv[8] = {w0.x, w0.y, w0.z, w0.w, w1.x, w1.y, w1.z, w1.w};
#pragma unroll
      for (int i = 0; i < 8; ++i)
#pragma unroll
        for (int j = 0; j < 8; ++j) acc[i][j] += xv[i] * wv[j];
    }
  }
#undef LOADREGS
#undef STOREREGS

  // epilogue: attention dots (short live range for aS/aD)
  float aS[8], aD[8];
#pragma unroll
  for (int j = 0; j < 8; ++j) {
    aS[j] = av_src[head * HID + quar * 8 + j];
    aD[j] = av_dst[head * HID + quar * 8 + j];
  }
  float pdS[8], pdD[8];
#pragma unroll
  for (int i = 0; i < 8; ++i) {
    float s = 0.f, d = 0.f;
#pragma unroll
    for (int j = 0; j < 8; ++j) { s += acc[i][j] * aS[j]; d += acc[i][j] * aD[j]; }
    pdS[i] = s; pdD[i] = d;
  }
#pragma unroll
  for (int i = 0; i < 8; ++i) {
    pdS[i] += __shfl_xor(pdS[i], 1);  pdD[i] += __shfl_xor(pdD[i], 1);
    pdS[i] += __shfl_xor(pdS[i], 2);  pdD[i] += __shfl_xor(pdD[i], 2);
  }

  float mloc = -3.4e38f;
#pragma unroll
  for (int i = 0; i < 8; ++i) {
    int gr = row0 + r0 + i;
    if (gr < N_NODES) {
      float4* hrow = (float4*)&H[(size_t)gr * HF + c0];
      hrow[0] = make_float4(acc[i][0], acc[i][1], acc[i][2], acc[i][3]);
      hrow[1] = make_float4(acc[i][4], acc[i][5], acc[i][6], acc[i][7]);
      if (quar == 0) {
        AS[gr * HEADS + head] = pdS[i];
        AD[gr * HEADS + head] = pdD[i];
        mloc = fmaxf(mloc, pdS[i]);
      }
    }
  }
  // fused per-head max of AS -> M4 (block LDS reduce, then global atomic)
  if (quar == 0) atomicMax(&smax[head], fenc(mloc));
  __syncthreads();
  if (t < HEADS) atomicMax(&M4[t], smax[t]);
}

// ---------------- fused softmax + aggregation ----------------
// Half-wave (32 lanes) per node: each lane owns 4 columns (float4) of the
// 512B H row. 4 edges unrolled -> 8 independent csr->H gather chains per
// wave. e = exp(lrelu(as+ad) - m), m = lrelu(M_h + ad) >= true max.
template<bool CONCAT>
__global__ void __launch_bounds__(256) k_aggregate(
    const int* __restrict__ rs, const int* __restrict__ csr_src,
    const float* __restrict__ H, const float* __restrict__ AS,
    const float* __restrict__ AD, const unsigned* __restrict__ M4,
    const float* __restrict__ bias, float* __restrict__ OUT) {
  int n = blockIdx.x * 8 + (threadIdx.x >> 5);
  if (n >= N_NODES) return;
  int sl = threadIdx.x & 31;
  int c = sl * 4;                      // this lane's 4 columns
  int head = sl >> 3;
  int b = rs[n], e = rs[n + 1];

  float ad = AD[4 * n + head];
  float m = lrelu(fdec(M4[head]) + ad);

  float ax = 0.f, ay = 0.f, az = 0.f, aw = 0.f, den = 0.f;
  int jj = b;
  for (; jj + 3 < e; jj += 4) {        // 4 gather chains in flight
    int s0 = csr_src[jj];
    int s1 = csr_src[jj + 1];
    int s2 = csr_src[jj + 2];
    int s3 = csr_src[jj + 3];
    float e0 = __expf(lrelu(AS[4 * s0 + head] + ad) - m);
    float e1 = __expf(lrelu(AS[4 * s1 + head] + ad) - m);
    float e2 = __expf(lrelu(AS[4 * s2 + head] + ad) - m);
    float e3 = __expf(lrelu(AS[4 * s3 + head] + ad) - m);
    float4 h0 = *(const float4*)&H[(size_t)s0 * HF + c];
    float4 h1 = *(const float4*)&H[(size_t)s1 * HF + c];
    float4 h2 = *(const float4*)&H[(size_t)s2 * HF + c];
    float4 h3 = *(const float4*)&H[(size_t)s3 * HF + c];
    ax += h0.x * e0 + h1.x * e1 + h2.x * e2 + h3.x * e3;
    ay += h0.y * e0 + h1.y * e1 + h2.y * e2 + h3.y * e3;
    az += h0.z * e0 + h1.z * e1 + h2.z * e2 + h3.z * e3;
    aw += h0.w * e0 + h1.w * e1 + h2.w * e2 + h3.w * e3;
    den += (e0 + e1) + (e2 + e3);
  }
  for (; jj < e; ++jj) {
    int s0 = csr_src[jj];
    float e0 = __expf(lrelu(AS[4 * s0 + head] + ad) - m);
    float4 h0 = *(const float4*)&H[(size_t)s0 * HF + c];
    ax += h0.x * e0; ay += h0.y * e0; az += h0.z * e0; aw += h0.w * e0;
    den += e0;
  }

  float invd = 1.f / den;
  if (CONCAT) {
    float4 o;
    o.x = elu_f(ax * invd + bias[c]);
    o.y = elu_f(ay * invd + bias[c + 1]);
    o.z = elu_f(az * invd + bias[c + 2]);
    o.w = elu_f(aw * invd + bias[c + 3]);
    *(float4*)&OUT[(size_t)n * HF + c] = o;
  } else {
    // mean over heads: fold lanes sl^8, sl^16 (stay within the 32-lane half)
    ax *= invd; ay *= invd; az *= invd; aw *= invd;
    ax += __shfl_xor(ax, 8);  ay += __shfl_xor(ay, 8);
    az += __shfl_xor(az, 8);  aw += __shfl_xor(aw, 8);
    ax += __shfl_xor(ax, 16); ay += __shfl_xor(ay, 16);
    az += __shfl_xor(az, 16); aw += __shfl_xor(aw, 16);
    if (sl < 8) {
      int cc = sl * 4;                 // 0..28
      float4 o;
      o.x = elu_f(0.25f * ax + bias[cc]);
      o.y = elu_f(0.25f * ay + bias[cc + 1]);
      o.z = elu_f(0.25f * az + bias[cc + 2]);
      o.w = elu_f(0.25f * aw + bias[cc + 3]);
      *(float4*)&OUT[(size_t)n * HID + cc] = o;
    }
  }
}

// ---------------- global mean pool + MLP head (one wave per graph) ----------------
__global__ void __launch_bounds__(64) k_pool_mlp(
    const int* __restrict__ batch, const float* __restrict__ H3,
    const float* __restrict__ Wm1, const float* __restrict__ bm1,
    const float* __restrict__ Wm2, const float* __restrict__ bm2,
    float* __restrict__ OUT) {
  int g = blockIdx.x;
  int t = threadIdx.x;
  __shared__ float pooled[HID];
  int lo = 0, hi = N_NODES;
  while (lo < hi) { int mid = (lo + hi) >> 1; if (batch[mid] < g) lo = mid + 1; else hi = mid; }
  int start = lo;
  hi = N_NODES;
  while (lo < hi) { int mid = (lo + hi) >> 1; if (batch[mid] < g + 1) lo = mid + 1; else hi = mid; }
  int end = lo;
  if (t < HID) {
    float s = 0.f;
    for (int n = start; n < end; ++n) s += H3[(size_t)n * HID + t];
    float cnt = (float)(end - start);
    pooled[t] = s / fmaxf(cnt, 1.f);
  }
  __syncthreads();
  float z = bm1[t];
#pragma unroll
  for (int f = 0; f < HID; ++f) z += pooled[f] * Wm1[f * 64 + t];
  z = fmaxf(z, 0.f);
  float p = z * Wm2[t];
  for (int off = 32; off > 0; off >>= 1) p += __shfl_down(p, off);
  if (t == 0) OUT[g] = p + bm2[0];
}

extern "C" void kernel_launch(void* const* d_in, const int* in_sizes, int n_in,
                              void* d_out, int out_size, void* d_ws, size_t ws_size,
                              hipStream_t stream) {
  const float* x    = (const float*)d_in[0];
  const int*   ei   = (const int*)d_in[1];
  const int*   batch= (const int*)d_in[2];
  const float* W1   = (const float*)d_in[3];
  const float* a1s  = (const float*)d_in[4];
  const float* a1d  = (const float*)d_in[5];
  const float* b1   = (const float*)d_in[6];
  const float* W2   = (const float*)d_in[7];
  const float* a2s  = (const float*)d_in[8];
  const float* a2d  = (const float*)d_in[9];
  const float* b2   = (const float*)d_in[10];
  const float* W3   = (const float*)d_in[11];
  const float* a3s  = (const float*)d_in[12];
  const float* a3d  = (const float*)d_in[13];
  const float* b3   = (const float*)d_in[14];
  const float* Wm1  = (const float*)d_in[15];
  const float* bm1  = (const float*)d_in[16];
  const float* Wm2  = (const float*)d_in[17];
  const float* bm2  = (const float*)d_in[18];
  float* out = (float*)d_out;

  char* p = (char*)d_ws;
  auto take = [&](size_t bytes) { char* r = p; p += (bytes + 255) & ~(size_t)255; return r; };
  float*    bufA  = (float*)take((size_t)N_NODES * HF * 4);
  float*    bufB  = (float*)take((size_t)N_NODES * HF * 4);
  float*    AS    = (float*)take((size_t)N_NODES * HEADS * 4);
  float*    AD    = (float*)take((size_t)N_NODES * HEADS * 4);
  unsigned* M4    = (unsigned*)take(3 * 4 * 4);         // 3 layers x 4 heads
  int*      deg   = (int*)take((size_t)N_NODES * 4);    // reused as fill counters
  int*      rs    = (int*)take((size_t)(N_NODES + 1) * 4);
  int*      csr   = (int*)take((size_t)ET * 4);
  int*      bsums = (int*)take((size_t)512 * 4);

  unsigned* M4a = M4;
  unsigned* M4b = M4 + 4;
  unsigned* M4c = M4 + 8;

  const int nb_scan = (N_NODES + 255) / 256;  // 391

  hipMemsetAsync(deg, 0, (size_t)N_NODES * 4, stream);
  hipMemsetAsync(M4, 0, 48, stream);
  k_count<<<(ET + 255) / 256, 256, 0, stream>>>(ei, deg);
  k_scan1<<<nb_scan, 256, 0, stream>>>(deg, rs, bsums);
  k_scan2<<<1, 512, 0, stream>>>(bsums, nb_scan);
  k_scan3<<<nb_scan, 256, 0, stream>>>(rs, bsums);
  hipMemsetAsync(deg, 0, (size_t)N_NODES * 4, stream);
  k_fill<<<(ET + 255) / 256, 256, 0, stream>>>(ei, rs, deg, csr);

  const int gb = (N_NODES + 127) / 128;       // 782 blocks of 128 rows
  const int ab = (N_NODES + 7) / 8;           // aggregate: 8 nodes/block

  // layer 1 (K=64)
  k_gemm_attn<IN_DIM><<<gb, 256, 0, stream>>>(x, W1, a1s, a1d, bufA, AS, AD, M4a);
  k_aggregate<true><<<ab, 256, 0, stream>>>(rs, csr, bufA, AS, AD, M4a, b1, bufB);
  // layer 2 (K=128)
  k_gemm_attn<HF><<<gb, 256, 0, stream>>>(bufB, W2, a2s, a2d, bufA, AS, AD, M4b);
  k_aggregate<true><<<ab, 256, 0, stream>>>(rs, csr, bufA, AS, AD, M4b, b2, bufB);
  // layer 3 (K=128, concat=False -> head mean)
  k_gemm_attn<HF><<<gb, 256, 0, stream>>>(bufB, W3, a3s, a3d, bufA, AS, AD, M4c);
  k_aggregate<false><<<ab, 256, 0, stream>>>(rs, csr, bufA, AS, AD, M4c, b3, bufB);
  // pool + MLP
  k_pool_mlp<<<N_GRAPHS, 64, 0, stream>>>(batch, bufB, Wm1, bm1, Wm2, bm2, out);
}